// Round 9
// baseline (202.452 us; speedup 1.0000x reference)
//
#include <hip/hip_runtime.h>
#include <hip/hip_bf16.h>

#define DIM   1024
#define NHEAD 16
#define HD    64
#define SEQ   4096

typedef __attribute__((ext_vector_type(4))) float  f32x4;
typedef __attribute__((ext_vector_type(8))) __bf16 bf16x8;
typedef __attribute__((ext_vector_type(8))) _Float16 f16x8;
typedef __attribute__((ext_vector_type(4))) short  short4v;
typedef __attribute__((ext_vector_type(4))) unsigned uint4v;

template <int B> struct ICt { static constexpr int v = B; };

// fp32 -> bf16 RNE
static __device__ __forceinline__ short f2bf(float f) {
  unsigned u = __builtin_bit_cast(unsigned, f);
  u += 0x7fffu + ((u >> 16) & 1u);
  return (short)(u >> 16);
}
static __device__ __forceinline__ float bflo(unsigned u) {
  return __builtin_bit_cast(float, u << 16);
}
static __device__ __forceinline__ float bfhi(unsigned u) {
  return __builtin_bit_cast(float, u & 0xFFFF0000u);
}

// pack two fp32 -> packed f16 pair (v_cvt_pkrtz_f16_f32), as raw u32
static __device__ __forceinline__ unsigned pkf16(float a, float b) {
  return __builtin_bit_cast(unsigned, __builtin_amdgcn_cvt_pkrtz(a, b));
}

// async global->LDS, 16B per lane: per-lane GLOBAL gather, LDS dest =
// wave-uniform base + lane*16.
static __device__ __forceinline__ void gl2lds16(const void* g, void* l) {
  __builtin_amdgcn_global_load_lds(
      (__attribute__((address_space(1))) void*)g,
      (__attribute__((address_space(3))) void*)l, 16, 0, 0);
}

// Cast x + 4 weights to bf16.
__global__ void cast_kernel(const float* __restrict__ x,
                            const float* __restrict__ Wq,
                            const float* __restrict__ Wk,
                            const float* __restrict__ Wv,
                            const float* __restrict__ Wo,
                            short* __restrict__ xb,
                            short* __restrict__ wb) {
  int b = blockIdx.x;
  const float* src;
  short* dst;
  if (b < 4096) {
    src = x + (size_t)b * 1024;
    dst = xb + (size_t)b * 1024;
  } else {
    int t = b - 4096;
    int w = t >> 10;
    size_t off = (size_t)(t & 1023) * 1024;
    src = (w == 0 ? Wq : w == 1 ? Wk : w == 2 ? Wv : Wo) + off;
    dst = wb + (size_t)w * 1048576 + off;
  }
  int i = threadIdx.x;
  float4 v = ((const float4*)src)[i];
  short4v o;
  o.x = f2bf(v.x); o.y = f2bf(v.y); o.z = f2bf(v.z); o.w = f2bf(v.w);
  ((short4v*)dst)[i] = o;
}

// 128x128 NT GEMM tile body: C[M,N] = A[M,K]*B[N,K]^T, bf16 K-major inputs.
// OUT: 0 = bf16 store, 2 = f16 store.
// LDS XOR swizzle (keep): un-swizzled frag reads were 8-way bank conflicts
// (1.05M SQ_LDS_BANK_CONFLICT measured round 11).
template <int OUT>
static __device__ __forceinline__ void gemm_tile(const short* __restrict__ A,
                                                 const short* __restrict__ B,
                                                 void* __restrict__ Cv,
                                                 int N, int K, int bm, int bn,
                                                 short* As, short* Bs) {
  const int tid  = threadIdx.x;
  const int wave = tid >> 6;
  const int lane = tid & 63;
  const int quad = lane >> 4;
  const int l15  = lane & 15;
  const int wm = (wave >> 1) * 64;
  const int wn = (wave & 1) * 64;
  const int sw = (quad ^ ((l15 >> 1) & 3)) * 8;   // read-side swizzle

  f32x4 acc[4][4];
#pragma unroll
  for (int i = 0; i < 4; ++i)
#pragma unroll
    for (int j = 0; j < 4; ++j) acc[i][j] = (f32x4){0.f, 0.f, 0.f, 0.f};

  for (int k0 = 0; k0 < K; k0 += 32) {
#pragma unroll
    for (int it = 0; it < 2; ++it) {
      int c   = it * 256 + wave * 64 + lane;       // 16B slot id, 512 total
      int row = c >> 2;
      int ce  = ((c & 3) ^ ((c >> 3) & 3)) * 8;    // swizzled global col-block
      gl2lds16(A + (size_t)(bm + row) * K + k0 + ce,
               As + (size_t)(it * 256 + wave * 64) * 8);
      gl2lds16(B + (size_t)(bn + row) * K + k0 + ce,
               Bs + (size_t)(it * 256 + wave * 64) * 8);
    }
    __syncthreads();

    bf16x8 af[4], bfr[4];
#pragma unroll
    for (int mt = 0; mt < 4; ++mt)
      af[mt] = *(const bf16x8*)&As[(wm + mt * 16 + l15) * 32 + sw];
#pragma unroll
    for (int nt = 0; nt < 4; ++nt)
      bfr[nt] = *(const bf16x8*)&Bs[(wn + nt * 16 + l15) * 32 + sw];
#pragma unroll
    for (int mt = 0; mt < 4; ++mt)
#pragma unroll
      for (int nt = 0; nt < 4; ++nt)
        acc[mt][nt] = __builtin_amdgcn_mfma_f32_16x16x32_bf16(
            af[mt], bfr[nt], acc[mt][nt], 0, 0, 0);
    __syncthreads();
  }

  short* C = (short*)Cv;
#pragma unroll
  for (int mt = 0; mt < 4; ++mt)
#pragma unroll
    for (int nt = 0; nt < 4; ++nt)
#pragma unroll
      for (int r = 0; r < 4; ++r) {
        size_t idx = (size_t)(bm + wm + mt * 16 + quad * 4 + r) * N +
                     bn + wn + nt * 16 + l15;
        if (OUT == 0)
          C[idx] = f2bf(acc[mt][nt][r]);
        else
          C[idx] = (short)(pkf16(acc[mt][nt][r], 0.f) & 0xFFFFu);
      }
}

// Fused projection launch: blocks 0..511 compute QK = x·[Wq;Wk]^T (bf16,
// [4096][2048]); blocks 512..767 compute Vt = Wv·x^T (F16, [1024][4096]).
__global__ __launch_bounds__(256, 2) void proj_kernel(const short* __restrict__ xb,
                                                      const short* __restrict__ wqk,
                                                      const short* __restrict__ wv,
                                                      short* __restrict__ QKb,
                                                      short* __restrict__ Vtb) {
  __shared__ short As[128 * 32];
  __shared__ short Bs[128 * 32];
  int b = blockIdx.x;
  if (b < 512) {
    gemm_tile<0>(xb, wqk, QKb, 2048, 1024, (b >> 4) * 128, (b & 15) * 128, As, Bs);
  } else {
    int t = b - 512;
    gemm_tile<2>(wv, xb, Vtb, 4096, 1024, (t >> 5) * 128, (t & 31) * 128, As, Bs);
  }
}

// Flash attention, causal, key-split KS=2, NO ATOMICS. (= round-6 version,
// verified 51.7us; round-7's q-tile pairing regressed -- reverted.)
// KS=2 with 128-key PHASES: each barrier-phase stages+computes TWO 64-key
// subtiles (4 LDS subtile buffers, 64 KB). Grid 512 = 2 blocks/CU
// all-resident. Balanced y-remap: blocks land on CUs as {c, c+256}; y =
// (t<8 ? 15-t : t-8) makes every CU's pair sum to 17 phases. 2 partial
// buffers (both fit in workspace; frees d_out for the fused epilogue GEMM).
// Kept from verified rounds: 8 waves x 32 q-rows (2 strips sharing all K/V
// LDS reads -- the LDS-amortization win), single-barrier ping-pong (stage
// pair i+1 issues BEFORE compute of pair i; one barrier per phase drains
// last phase's DMA), compile-time LDS bases via ICt, hoisted LDS base
// pointers, f16 PV, raw v_exp_f32, unnormalized partials pOz + lp[z].
// launch_bounds(512,4): cap 128 VGPR (round-19's (512,8) spill disaster:
// WRITE 34->113MB must not recur).
// NEVER index a frag buffer with a runtime value (round-5 scratch spill).
__global__ __launch_bounds__(512, 4) void flash_attn(const short* __restrict__ QK,
                                                     const short* __restrict__ Vt,
                                                     short* __restrict__ pO0,
                                                     short* __restrict__ pO1,
                                                     float* __restrict__ lp) {
  const int bb  = blockIdx.x;
  const int z   = bb & 1;              // key split: 64-key tile jt ≡ z (mod 2)
  const int h   = (bb >> 1) & 15;
  const int t   = bb >> 5;             // 0..15
  const int y   = (t < 8) ? (15 - t) : (t - 8);  // balanced pairs sum 17
  // jtB = 4y+3 >= 3 > z always: every split live, nst = y+1 pair-phases.

  __shared__ short Ks[4 * 4096];       // 32 KB: 4 x 64-key K subtiles
  __shared__ short Vs[4 * 4096];       // 32 KB (f16 payload)

  const int wave = threadIdx.x >> 6;   // 0..7
  const int lane = threadIdx.x & 63;
  const int quad = lane >> 4;
  const int l15  = lane & 15;
  const int qw   = y * 256 + wave * 32;  // this wave's 32 q rows (2 strips)
  const int jtd  = 4 * y + (wave >> 1);  // diag 64-key tile for this wave

  const short* Qp = QK + h * HD;
  const short* Kp = QK + 1024 + h * HD;
  const short* Vp = Vt + (size_t)(h * HD) * SEQ;

  // Q frags (loaded once): strips A (rows qw+0..15) and B (rows qw+16..31)
  bf16x8 qf0[2], qf1[2];
#pragma unroll
  for (int kk = 0; kk < 2; ++kk) {
    qf0[kk] = *(const bf16x8*)&Qp[(size_t)(qw + l15) * 2048 + kk * 32 + quad * 8];
    qf1[kk] = *(const bf16x8*)&Qp[(size_t)(qw + 16 + l15) * 2048 + kk * 32 + quad * 8];
  }

  f32x4 oaccA[4], oaccB[4];
  f32x4 laccA = (f32x4){0.f, 0.f, 0.f, 0.f};
  f32x4 laccB = (f32x4){0.f, 0.f, 0.f, 0.f};
#pragma unroll
  for (int nt = 0; nt < 4; ++nt) {
    oaccA[nt] = (f32x4){0.f, 0.f, 0.f, 0.f};
    oaccB[nt] = (f32x4){0.f, 0.f, 0.f, 0.f};
  }

  const float SC = 0.125f * 1.44269504088896340736f;  // /sqrt(64) * log2(e)

  f16x8 ones16;
  { uint4v o1 = {0x3C003C00u, 0x3C003C00u, 0x3C003C00u, 0x3C003C00u};
    ones16 = __builtin_bit_cast(f16x8, o1); }

  // hoisted LDS read base pointers (per-subtile reads fold to
  // [invariant reg + literal offset])
  const short* kq = Ks + quad * 512 + l15 * 8;
  const short* vq = Vs + quad * 512 + l15 * 8;

  // staging: wave nw does chunk pair (nw&3, nw>>2) of each subtile:
  // 2 K + 2 V gl2lds per wave per pair-phase.
  const int ow = wave & 3;
  const int hf = wave >> 2;
  const int g = ((lane >> 5) & 1) * 32 + ((lane >> 4) & 1) * 4 +
                ((lane >> 2) & 3) * 8 + (lane & 3);
  const short* kstage = Kp + (size_t)(z * 64 + g) * 2048 + ow * 16 + hf * 8;
  const short* vstage = Vp + (size_t)lane * SEQ + z * 64 + ow * 16 + hf * 8;
  short* ksl = Ks + ow * 1024 + hf * 512;
  short* vsl = Vs + ow * 1024 + hf * 512;
  const size_t KPAIR = (size_t)2 * 64 * 2048;  // 2nd subtile of pair (jt+2)
  const size_t KADV  = (size_t)4 * 64 * 2048;  // phase stride (jt+=4)
  const int    VPAIR = 2 * 64;
  const int    VADV  = 4 * 64;

  const int qv0 = qw + l15;
  const int qv1 = qw + 16 + l15;

  // one 64-key subtile for both strips; LDS base is COMPILE-TIME
  auto subtile = [&](int jtc, auto bc) {
    constexpr int base = decltype(bc)::v * 4096;
    if (jtc > jtd) return;             // fully-masked future tile: contributes 0

    f32x4 s0[4], s1[4];
#pragma unroll
    for (int mt = 0; mt < 4; ++mt) {
      bf16x8 k0 = *(const bf16x8*)(kq + base + mt * 128);
      bf16x8 k1 = *(const bf16x8*)(kq + base + 2048 + mt * 128);
      s0[mt] = (f32x4){0.f, 0.f, 0.f, 0.f};
      s0[mt] = __builtin_amdgcn_mfma_f32_16x16x32_bf16(k0, qf0[0], s0[mt], 0, 0, 0);
      s0[mt] = __builtin_amdgcn_mfma_f32_16x16x32_bf16(k1, qf0[1], s0[mt], 0, 0, 0);
      s1[mt] = (f32x4){0.f, 0.f, 0.f, 0.f};
      s1[mt] = __builtin_amdgcn_mfma_f32_16x16x32_bf16(k0, qf1[0], s1[mt], 0, 0, 0);
      s1[mt] = __builtin_amdgcn_mfma_f32_16x16x32_bf16(k1, qf1[1], s1[mt], 0, 0, 0);
    }

    unsigned pk0[4][2], pk1[4][2];
    const bool domask = (jtc == jtd);  // wave-uniform
#pragma unroll
    for (int mt = 0; mt < 4; ++mt) {
      float pr[4], qr[4];
#pragma unroll
      for (int r = 0; r < 4; ++r) {
        pr[r] = fmaf(s0[mt][r], SC, -12.0f);
        qr[r] = fmaf(s1[mt][r], SC, -12.0f);
      }
      if (domask) {
        int kb0 = jtc * 64 + (mt >> 1) * 32 + quad * 8 + (mt & 1) * 4;
#pragma unroll
        for (int r = 0; r < 4; ++r) {
          if (kb0 + r > qv0) pr[r] = -1e30f;
          if (kb0 + r > qv1) qr[r] = -1e30f;
        }
      }
#pragma unroll
      for (int r = 0; r < 4; ++r) {
        pr[r] = __builtin_amdgcn_exp2f(pr[r]);
        qr[r] = __builtin_amdgcn_exp2f(qr[r]);
      }
      pk0[mt][0] = pkf16(pr[0], pr[1]);
      pk0[mt][1] = pkf16(pr[2], pr[3]);
      pk1[mt][0] = pkf16(qr[0], qr[1]);
      pk1[mt][1] = pkf16(qr[2], qr[3]);
    }

#pragma unroll
    for (int kk = 0; kk < 2; ++kk) {
      f16x8 vb[4];
#pragma unroll
      for (int nt = 0; nt < 4; ++nt)
        vb[nt] = *(const f16x8*)(vq + base + kk * 2048 + nt * 128);
      f16x8 pa0, pa1;
      { uint4v t2 = {pk0[2 * kk][0], pk0[2 * kk][1],
                     pk0[2 * kk + 1][0], pk0[2 * kk + 1][1]};
        pa0 = __builtin_bit_cast(f16x8, t2); }
      { uint4v t2 = {pk1[2 * kk][0], pk1[2 * kk][1],
                     pk1[2 * kk + 1][0], pk1[2 * kk + 1][1]};
        pa1 = __builtin_bit_cast(f16x8, t2); }
      laccA = __builtin_amdgcn_mfma_f32_16x16x32_f16(pa0, ones16, laccA, 0, 0, 0);
      laccB = __builtin_amdgcn_mfma_f32_16x16x32_f16(pa1, ones16, laccB, 0, 0, 0);
#pragma unroll
      for (int nt = 0; nt < 4; ++nt) {
        oaccA[nt] = __builtin_amdgcn_mfma_f32_16x16x32_f16(pa0, vb[nt], oaccA[nt], 0, 0, 0);
        oaccB[nt] = __builtin_amdgcn_mfma_f32_16x16x32_f16(pa1, vb[nt], oaccB[nt], 0, 0, 0);
      }
    }
  };

  const int nst = y + 1;               // pair-phases (uniform in z)

  // prologue: stage pair 0 (subtiles jt=z, z+2) into buffers 0,1
  gl2lds16(kstage,         ksl);
  gl2lds16(kstage + KPAIR, ksl + 4096);
  gl2lds16(vstage,         vsl);
  gl2lds16(vstage + VPAIR, vsl + 4096);
  kstage += KADV; vstage += VADV;

  // x2-unrolled ping-pong over buffer PAIRS (bases 0/4096 vs 8192/12288)
  int i = 0, jt = z;
  for (;;) {
    // even phase: compute pair in bufs 0,1; stage next pair into bufs 2,3
    __syncthreads();                   // drains stage issued last phase
    if (i + 1 < nst) {                 // block-uniform
      gl2lds16(kstage,         ksl + 8192);
      gl2lds16(kstage + KPAIR, ksl + 12288);
      gl2lds16(vstage,         vsl + 8192);
      gl2lds16(vstage + VPAIR, vsl + 12288);
      kstage += KADV; vstage += VADV;
    }
    subtile(jt,     ICt<0>{});         // staging latency hides under these
    subtile(jt + 2, ICt<1>{});
    ++i; jt += 4;
    if (i >= nst) break;

    // odd phase: compute pair in bufs 2,3; stage next pair into bufs 0,1
    __syncthreads();
    if (i + 1 < nst) {
      gl2lds16(kstage,         ksl);
      gl2lds16(kstage + KPAIR, ksl + 4096);
      gl2lds16(vstage,         vsl);
      gl2lds16(vstage + VPAIR, vsl + 4096);
      kstage += KADV; vstage += VADV;
    }
    subtile(jt,     ICt<2>{});
    subtile(jt + 2, ICt<3>{});
    ++i; jt += 4;
    if (i >= nst) break;
  }

  // ---- epilogue: plain coalesced bf16 partial stores (NO atomics)
  short* pO = z ? pO1 : pO0;
#pragma unroll
  for (int nt = 0; nt < 4; ++nt)
#pragma unroll
    for (int r = 0; r < 4; ++r) {
      pO[(size_t)(qw + quad * 4 + r) * DIM + h * HD + nt * 16 + l15] =
          f2bf(oaccA[nt][r]);
      pO[(size_t)(qw + 16 + quad * 4 + r) * DIM + h * HD + nt * 16 + l15] =
          f2bf(oaccB[nt][r]);
    }
  if (l15 == 0) {
#pragma unroll
    for (int r = 0; r < 4; ++r) {
      lp[(size_t)z * SEQ * NHEAD + (size_t)(qw + quad * 4 + r) * NHEAD + h] =
          laccA[r];
      lp[(size_t)z * SEQ * NHEAD + (size_t)(qw + 16 + quad * 4 + r) * NHEAD + h] =
          laccB[r];
    }
  }
}

// Final O-projection with FUSED COMBINE, round-9 fix: the round-8 version
// exposed the full pO-load latency every K-step (sync load -> wait ->
// ds_write on the critical path: +15us). Now the loads for step k0+32 are
// issued INSIDE step k0's MFMA phase (after the first barrier), giving
// them ~the whole ds_read+MFMA phase to complete before the second
// barrier's drain (T14 async-STAGE split, depth 1). ds_write at the top
// of step k0 uses registers loaded one step earlier -- zero wait.
// Numerics identical to round-8 (same values, same double rounding).
// 64x128 tiles -> 512 blocks = 2 blocks/CU resident. 12 KB LDS.
__global__ __launch_bounds__(256, 2) void gemm_out(const short* __restrict__ pO0,
                                                   const short* __restrict__ pO1,
                                                   const float* __restrict__ lp,
                                                   const short* __restrict__ B,
                                                   float* __restrict__ C) {
  __shared__ short As[64 * 32];   // 4 KB
  __shared__ short Bs[128 * 32];  // 8 KB
  const int tid  = threadIdx.x;
  const int wave = tid >> 6;
  const int lane = tid & 63;
  const int quad = lane >> 4;
  const int l15  = lane & 15;
  const int bm = (int)(blockIdx.x >> 3) * 64;
  const int bn = (int)(blockIdx.x & 7) * 128;
  const int wn = wave * 32;
  const int sw = (quad ^ ((l15 >> 1) & 3)) * 8;
  const size_t LS = (size_t)SEQ * NHEAD;

  // A-stage constants (fixed per thread): row and swizzled col-block
  const int arow = tid >> 2;
  const int ace  = ((tid & 3) ^ ((tid >> 3) & 3)) * 8;
  const size_t abase = (size_t)(bm + arow) * 1024 + ace;  // + k0
  const size_t lbase = (size_t)(bm + arow) * NHEAD;       // + (k0+ace)>>6

  f32x4 acc[4][2];
#pragma unroll
  for (int i = 0; i < 4; ++i)
#pragma unroll
    for (int j = 0; j < 2; ++j) acc[i][j] = (f32x4){0.f, 0.f, 0.f, 0.f};

  // prologue: load k0=0 operands (one exposed latency, once)
  uint4v pa = *(const uint4v*)(pO0 + abase);
  uint4v pb = *(const uint4v*)(pO1 + abase);
  float  la, lb;
  { size_t li = lbase + ((unsigned)ace >> 6);
    la = lp[li]; lb = lp[LS + li]; }

  for (int k0 = 0; k0 < 1024; k0 += 32) {
    {  // A: combine (pa+pb)*rinv -> Z bf16 -> ds_write to slot As[tid*8]
      float rinv = 1.0f / (la + lb);
      uint4v o;
#pragma unroll
      for (int i = 0; i < 4; ++i) {
        float s0 = (bflo(pa[i]) + bflo(pb[i])) * rinv;
        float s1 = (bfhi(pa[i]) + bfhi(pb[i])) * rinv;
        unsigned p0 = (unsigned)(unsigned short)f2bf(s0);
        unsigned p1 = (unsigned)(unsigned short)f2bf(s1);
        o[i] = p0 | (p1 << 16);
      }
      *(uint4v*)(As + (size_t)tid * 8) = o;   // ds_write_b128, same slot as DMA
    }
#pragma unroll
    for (int it = 0; it < 2; ++it) {  // B: 128x32 = 512 slots (async DMA)
      int c = it * 256 + tid;
      int row = c >> 2;
      int ce = ((c & 3) ^ ((c >> 3) & 3)) * 8;
      gl2lds16(B + (size_t)(bn + row) * 1024 + k0 + ce,
               Bs + (size_t)(it * 256 + wave * 64) * 8);
    }
    __syncthreads();   // waits ds_write (lgkmcnt) AND gl2lds (vmcnt)

    // prefetch step k0+32 during the ds_read+MFMA phase (depth-1 pipeline)
    const bool more = (k0 + 32 < 1024);
    uint4v na, nb; float nla, nlb;
    if (more) {
      na = *(const uint4v*)(pO0 + abase + k0 + 32);
      nb = *(const uint4v*)(pO1 + abase + k0 + 32);
      size_t li = lbase + ((unsigned)(k0 + 32 + ace) >> 6);
      nla = lp[li]; nlb = lp[LS + li];
    }

    bf16x8 af[4], bfr[2];
#pragma unroll
    for (int mt = 0; mt < 4; ++mt)
      af[mt] = *(const bf16x8*)&As[(mt * 16 + l15) * 32 + sw];
#pragma unroll
    for (int nt = 0; nt < 2; ++nt)
      bfr[nt] = *(const bf16x8*)&Bs[(wn + nt * 16 + l15) * 32 + sw];
#pragma unroll
    for (int mt = 0; mt < 4; ++mt)
#pragma unroll
      for (int nt = 0; nt < 2; ++nt)
        acc[mt][nt] = __builtin_amdgcn_mfma_f32_16x16x32_bf16(
            af[mt], bfr[nt], acc[mt][nt], 0, 0, 0);
    __syncthreads();

    if (more) { pa = na; pb = nb; la = nla; lb = nlb; }
  }

#pragma unroll
  for (int mt = 0; mt < 4; ++mt)
#pragma unroll
    for (int nt = 0; nt < 2; ++nt)
#pragma unroll
      for (int r = 0; r < 4; ++r)
        C[(size_t)(bm + mt * 16 + quad * 4 + r) * 1024 + bn + wn + nt * 16 + l15] =
            acc[mt][nt][r];
}

extern "C" void kernel_launch(void* const* d_in, const int* in_sizes, int n_in,
                              void* d_out, int out_size, void* d_ws, size_t ws_size,
                              hipStream_t stream) {
  const float* x  = (const float*)d_in[0];
  const float* Wq = (const float*)d_in[1];
  const float* Wk = (const float*)d_in[2];
  const float* Wv = (const float*)d_in[3];
  const float* Wo = (const float*)d_in[4];
  float* out = (float*)d_out;

  // Workspace layout (48 MB), regions overlaid by lifetime:
  //  [0,8)   xb (cast->proj)            ; pO0 bf16 (flash->gemm_out)
  //  [8,12)  wq,wk (cast->proj)         ; lp fp32 [2][SEQ][NHEAD] (flash->gemm_out)
  //  [12,14) wv (cast->proj)
  //  [14,16) wo (cast->gemm_out, live to end)
  //  [16,32) QKb bf16 (proj->flash)
  //  [32,40) Vtb F16 (proj->flash)
  //  [40,48) pO1 bf16 (flash->gemm_out)
  char* ws   = (char*)d_ws;
  short* xb  = (short*)(ws);
  short* wqb = (short*)(ws + (size_t)8 * 1024 * 1024);
  short* wvb = wqb + 2 * 1024 * 1024;
  short* wob = wqb + 3 * 1024 * 1024;
  short* QKb = (short*)(ws + (size_t)16 * 1024 * 1024);
  short* Vtb = (short*)(ws + (size_t)32 * 1024 * 1024);
  float* lpb = (float*)(ws + (size_t)8 * 1024 * 1024);
  short* pO0 = (short*)(ws);
  short* pO1 = (short*)(ws + (size_t)40 * 1024 * 1024);

  cast_kernel<<<dim3(8192), dim3(256), 0, stream>>>(x, Wq, Wk, Wv, Wo, xb, wqb);

  // fused Q+K projection (blocks 0..511) + V^T projection in f16 (512..767)
  proj_kernel<<<dim3(768), dim3(256), 0, stream>>>(xb, wqb, wvb, QKb, Vtb);

  flash_attn<<<dim3(512), dim3(512), 0, stream>>>(QKb, Vtb, pO0, pO1, lpb);

  // O-projection with fused combine (reads partials directly)
  gemm_out<<<dim3(512), dim3(256), 0, stream>>>(pO0, pO1, lpb, wob, out);
}

// Round 10
// 201.433 us; speedup vs baseline: 1.0051x; 1.0051x over previous
//
#include <hip/hip_runtime.h>
#include <hip/hip_bf16.h>

#define DIM   1024
#define NHEAD 16
#define HD    64
#define SEQ   4096

typedef __attribute__((ext_vector_type(4))) float  f32x4;
typedef __attribute__((ext_vector_type(8))) __bf16 bf16x8;
typedef __attribute__((ext_vector_type(8))) _Float16 f16x8;
typedef __attribute__((ext_vector_type(4))) short  short4v;
typedef __attribute__((ext_vector_type(4))) unsigned uint4v;

template <int B> struct ICt { static constexpr int v = B; };

// fp32 -> bf16 RNE
static __device__ __forceinline__ short f2bf(float f) {
  unsigned u = __builtin_bit_cast(unsigned, f);
  u += 0x7fffu + ((u >> 16) & 1u);
  return (short)(u >> 16);
}
static __device__ __forceinline__ float bflo(unsigned u) {
  return __builtin_bit_cast(float, u << 16);
}
static __device__ __forceinline__ float bfhi(unsigned u) {
  return __builtin_bit_cast(float, u & 0xFFFF0000u);
}

// pack two fp32 -> packed f16 pair (v_cvt_pkrtz_f16_f32), as raw u32
static __device__ __forceinline__ unsigned pkf16(float a, float b) {
  return __builtin_bit_cast(unsigned, __builtin_amdgcn_cvt_pkrtz(a, b));
}

// async global->LDS, 16B per lane: per-lane GLOBAL gather, LDS dest =
// wave-uniform base + lane*16.
static __device__ __forceinline__ void gl2lds16(const void* g, void* l) {
  __builtin_amdgcn_global_load_lds(
      (__attribute__((address_space(1))) void*)g,
      (__attribute__((address_space(3))) void*)l, 16, 0, 0);
}

// Cast x + 4 weights to bf16.
__global__ void cast_kernel(const float* __restrict__ x,
                            const float* __restrict__ Wq,
                            const float* __restrict__ Wk,
                            const float* __restrict__ Wv,
                            const float* __restrict__ Wo,
                            short* __restrict__ xb,
                            short* __restrict__ wb) {
  int b = blockIdx.x;
  const float* src;
  short* dst;
  if (b < 4096) {
    src = x + (size_t)b * 1024;
    dst = xb + (size_t)b * 1024;
  } else {
    int t = b - 4096;
    int w = t >> 10;
    size_t off = (size_t)(t & 1023) * 1024;
    src = (w == 0 ? Wq : w == 1 ? Wk : w == 2 ? Wv : Wo) + off;
    dst = wb + (size_t)w * 1048576 + off;
  }
  int i = threadIdx.x;
  float4 v = ((const float4*)src)[i];
  short4v o;
  o.x = f2bf(v.x); o.y = f2bf(v.y); o.z = f2bf(v.z); o.w = f2bf(v.w);
  ((short4v*)dst)[i] = o;
}

// 128x128 NT GEMM tile body: C[M,N] = A[M,K]*B[N,K]^T, bf16 K-major inputs.
// OUT: 0 = bf16 store, 2 = f16 store.
// LDS XOR swizzle (keep): un-swizzled frag reads were 8-way bank conflicts
// (1.05M SQ_LDS_BANK_CONFLICT measured round 11).
template <int OUT>
static __device__ __forceinline__ void gemm_tile(const short* __restrict__ A,
                                                 const short* __restrict__ B,
                                                 void* __restrict__ Cv,
                                                 int N, int K, int bm, int bn,
                                                 short* As, short* Bs) {
  const int tid  = threadIdx.x;
  const int wave = tid >> 6;
  const int lane = tid & 63;
  const int quad = lane >> 4;
  const int l15  = lane & 15;
  const int wm = (wave >> 1) * 64;
  const int wn = (wave & 1) * 64;
  const int sw = (quad ^ ((l15 >> 1) & 3)) * 8;   // read-side swizzle

  f32x4 acc[4][4];
#pragma unroll
  for (int i = 0; i < 4; ++i)
#pragma unroll
    for (int j = 0; j < 4; ++j) acc[i][j] = (f32x4){0.f, 0.f, 0.f, 0.f};

  for (int k0 = 0; k0 < K; k0 += 32) {
#pragma unroll
    for (int it = 0; it < 2; ++it) {
      int c   = it * 256 + wave * 64 + lane;       // 16B slot id, 512 total
      int row = c >> 2;
      int ce  = ((c & 3) ^ ((c >> 3) & 3)) * 8;    // swizzled global col-block
      gl2lds16(A + (size_t)(bm + row) * K + k0 + ce,
               As + (size_t)(it * 256 + wave * 64) * 8);
      gl2lds16(B + (size_t)(bn + row) * K + k0 + ce,
               Bs + (size_t)(it * 256 + wave * 64) * 8);
    }
    __syncthreads();

    bf16x8 af[4], bfr[4];
#pragma unroll
    for (int mt = 0; mt < 4; ++mt)
      af[mt] = *(const bf16x8*)&As[(wm + mt * 16 + l15) * 32 + sw];
#pragma unroll
    for (int nt = 0; nt < 4; ++nt)
      bfr[nt] = *(const bf16x8*)&Bs[(wn + nt * 16 + l15) * 32 + sw];
#pragma unroll
    for (int mt = 0; mt < 4; ++mt)
#pragma unroll
      for (int nt = 0; nt < 4; ++nt)
        acc[mt][nt] = __builtin_amdgcn_mfma_f32_16x16x32_bf16(
            af[mt], bfr[nt], acc[mt][nt], 0, 0, 0);
    __syncthreads();
  }

  short* C = (short*)Cv;
#pragma unroll
  for (int mt = 0; mt < 4; ++mt)
#pragma unroll
    for (int nt = 0; nt < 4; ++nt)
#pragma unroll
      for (int r = 0; r < 4; ++r) {
        size_t idx = (size_t)(bm + wm + mt * 16 + quad * 4 + r) * N +
                     bn + wn + nt * 16 + l15;
        if (OUT == 0)
          C[idx] = f2bf(acc[mt][nt][r]);
        else
          C[idx] = (short)(pkf16(acc[mt][nt][r], 0.f) & 0xFFFFu);
      }
}

// Fused projection launch: blocks 0..511 compute QK = x·[Wq;Wk]^T (bf16,
// [4096][2048]); blocks 512..767 compute Vt = Wv·x^T (F16, [1024][4096]).
__global__ __launch_bounds__(256, 2) void proj_kernel(const short* __restrict__ xb,
                                                      const short* __restrict__ wqk,
                                                      const short* __restrict__ wv,
                                                      short* __restrict__ QKb,
                                                      short* __restrict__ Vtb) {
  __shared__ short As[128 * 32];
  __shared__ short Bs[128 * 32];
  int b = blockIdx.x;
  if (b < 512) {
    gemm_tile<0>(xb, wqk, QKb, 2048, 1024, (b >> 4) * 128, (b & 15) * 128, As, Bs);
  } else {
    int t = b - 512;
    gemm_tile<2>(wv, xb, Vtb, 4096, 1024, (t >> 5) * 128, (t & 31) * 128, As, Bs);
  }
}

// Flash attention, causal, key-split KS=2, NO ATOMICS.
// ROUND-25 CHANGE: 4 waves x 64 q-rows (256 threads, 4 strips/wave).
// Evidence chain: the ONLY predictive model so far is LDS amortization
// (round-22: 16->32 rows/wave halved per-CU LDS reads, 69->51us). Per-CU
// LDS-read work = waves x subtile-bytes (each wave reads the WHOLE K/V
// subtile regardless of rows). 8x32 -> 4x64 halves it again: 128 -> 64
// ds_read_b128 per subtile per block (~20.5us -> ~10us of the 51us
// pipe-sum). VALU/MFMA totals unchanged. Staging: each wave now issues
// both half-chunks (8 gl2lds/pair-phase); LDS content bit-identical.
// Register budget (round-19 spill lesson): persistent = oacc 64 + lacc 16
// + qf 32 + ptrs ~16 ~= 128; QK+softmax fused PER-MT so sc dies fast
// (peak ~200-216) -> launch_bounds(256,2) caps 256 VGPR, 2 waves/SIMD =
// 2 blocks/CU (LDS 64KB x 2 = 128 <= 160). Spill signature to watch:
// WRITE_SIZE >> 18.4 MB.
// Kept (round-6 verified): KS=2 with 128-key pair-phases (4 LDS subtile
// buffers), balanced y-remap (CU pairs sum 17 phases), single-barrier
// ping-pong (stage pair i+1 BEFORE compute pair i), compile-time LDS
// bases via ICt, hoisted LDS base pointers, f16 PV, raw v_exp_f32,
// unnormalized partials pO0/pO1 + lp[z], combine normalizes.
// NEVER index a frag buffer with a runtime value (round-5 scratch spill).
__global__ __launch_bounds__(256, 2) void flash_attn(const short* __restrict__ QK,
                                                     const short* __restrict__ Vt,
                                                     short* __restrict__ pO0,
                                                     short* __restrict__ pO1,
                                                     float* __restrict__ lp) {
  const int bb  = blockIdx.x;
  const int z   = bb & 1;              // key split: 64-key tile jt ≡ z (mod 2)
  const int h   = (bb >> 1) & 15;
  const int t   = bb >> 5;             // 0..15
  const int y   = (t < 8) ? (15 - t) : (t - 8);  // balanced pairs sum 17
  // jtB = 4y+3 >= 3 > z always: every split live, nst = y+1 pair-phases.

  __shared__ short Ks[4 * 4096];       // 32 KB: 4 x 64-key K subtiles
  __shared__ short Vs[4 * 4096];       // 32 KB (f16 payload)

  const int wave = threadIdx.x >> 6;   // 0..3
  const int lane = threadIdx.x & 63;
  const int quad = lane >> 4;
  const int l15  = lane & 15;
  const int qw   = y * 256 + wave * 64;  // this wave's 64 q rows (4 strips)
  const int jtd  = 4 * y + wave;         // diag 64-key tile for this wave

  const short* Qp = QK + h * HD;
  const short* Kp = QK + 1024 + h * HD;
  const short* Vp = Vt + (size_t)(h * HD) * SEQ;

  // Q frags (loaded once): strips s=0..3 at rows qw + s*16 + l15
  bf16x8 qf[4][2];
#pragma unroll
  for (int s = 0; s < 4; ++s)
#pragma unroll
    for (int kk = 0; kk < 2; ++kk)
      qf[s][kk] = *(const bf16x8*)&Qp[(size_t)(qw + s * 16 + l15) * 2048 +
                                      kk * 32 + quad * 8];

  f32x4 oacc[4][4];                    // [strip][nt]
  f32x4 lacc[4];
#pragma unroll
  for (int s = 0; s < 4; ++s) {
    lacc[s] = (f32x4){0.f, 0.f, 0.f, 0.f};
#pragma unroll
    for (int nt = 0; nt < 4; ++nt) oacc[s][nt] = (f32x4){0.f, 0.f, 0.f, 0.f};
  }

  const float SC = 0.125f * 1.44269504088896340736f;  // /sqrt(64) * log2(e)

  f16x8 ones16;
  { uint4v o1 = {0x3C003C00u, 0x3C003C00u, 0x3C003C00u, 0x3C003C00u};
    ones16 = __builtin_bit_cast(f16x8, o1); }

  // hoisted LDS read base pointers (per-subtile reads fold to
  // [invariant reg + literal offset])
  const short* kq = Ks + quad * 512 + l15 * 8;
  const short* vq = Vs + quad * 512 + l15 * 8;

  // staging: wave w stages chunks (ow=w, hf=0) and (ow=w, hf=1) of each
  // subtile: 4 K + 4 V gl2lds per wave per pair-phase. LDS content
  // bit-identical to the verified 8-wave layout.
  const int g = ((lane >> 5) & 1) * 32 + ((lane >> 4) & 1) * 4 +
                ((lane >> 2) & 3) * 8 + (lane & 3);
  const short* kstage = Kp + (size_t)(z * 64 + g) * 2048 + wave * 16;
  const short* vstage = Vp + (size_t)lane * SEQ + z * 64 + wave * 16;
  short* ksl = Ks + wave * 1024;       // hf=0 chunk; hf=1 at +512
  short* vsl = Vs + wave * 1024;
  const size_t KPAIR = (size_t)2 * 64 * 2048;  // 2nd subtile of pair (jt+2)
  const size_t KADV  = (size_t)4 * 64 * 2048;  // phase stride (jt+=4)
  const int    VPAIR = 2 * 64;
  const int    VADV  = 4 * 64;

  // one 64-key subtile for all 4 strips; LDS base is COMPILE-TIME.
  // QK+softmax fused per-mt so sc lives briefly (register-pressure diet).
  auto subtile = [&](int jtc, auto bc) {
    constexpr int base = decltype(bc)::v * 4096;
    if (jtc > jtd) return;             // fully-masked future tile: contributes 0

    unsigned pk[4][4][2];              // [strip][mt][half]
    const bool domask = (jtc == jtd);  // wave-uniform
#pragma unroll
    for (int mt = 0; mt < 4; ++mt) {
      bf16x8 k0 = *(const bf16x8*)(kq + base + mt * 128);
      bf16x8 k1 = *(const bf16x8*)(kq + base + 2048 + mt * 128);
      const int kb0 = jtc * 64 + (mt >> 1) * 32 + quad * 8 + (mt & 1) * 4;
#pragma unroll
      for (int s = 0; s < 4; ++s) {
        f32x4 sc = (f32x4){0.f, 0.f, 0.f, 0.f};
        sc = __builtin_amdgcn_mfma_f32_16x16x32_bf16(k0, qf[s][0], sc, 0, 0, 0);
        sc = __builtin_amdgcn_mfma_f32_16x16x32_bf16(k1, qf[s][1], sc, 0, 0, 0);
        float pr[4];
#pragma unroll
        for (int r = 0; r < 4; ++r) pr[r] = fmaf(sc[r], SC, -12.0f);
        if (domask) {
          const int qv = qw + s * 16 + l15;
#pragma unroll
          for (int r = 0; r < 4; ++r)
            if (kb0 + r > qv) pr[r] = -1e30f;
        }
#pragma unroll
        for (int r = 0; r < 4; ++r) pr[r] = __builtin_amdgcn_exp2f(pr[r]);
        pk[s][mt][0] = pkf16(pr[0], pr[1]);
        pk[s][mt][1] = pkf16(pr[2], pr[3]);
      }
    }

#pragma unroll
    for (int kk = 0; kk < 2; ++kk) {
      f16x8 vb[4];
#pragma unroll
      for (int nt = 0; nt < 4; ++nt)
        vb[nt] = *(const f16x8*)(vq + base + kk * 2048 + nt * 128);
#pragma unroll
      for (int s = 0; s < 4; ++s) {
        f16x8 pa;
        { uint4v t2 = {pk[s][2 * kk][0], pk[s][2 * kk][1],
                       pk[s][2 * kk + 1][0], pk[s][2 * kk + 1][1]};
          pa = __builtin_bit_cast(f16x8, t2); }
        lacc[s] = __builtin_amdgcn_mfma_f32_16x16x32_f16(pa, ones16, lacc[s], 0, 0, 0);
#pragma unroll
        for (int nt = 0; nt < 4; ++nt)
          oacc[s][nt] = __builtin_amdgcn_mfma_f32_16x16x32_f16(pa, vb[nt], oacc[s][nt], 0, 0, 0);
      }
    }
  };

  const int nst = y + 1;               // pair-phases (uniform in z)

  // prologue: stage pair 0 (subtiles jt=z, z+2) into buffers 0,1
  gl2lds16(kstage,             ksl);
  gl2lds16(kstage + 8,         ksl + 512);
  gl2lds16(kstage + KPAIR,     ksl + 4096);
  gl2lds16(kstage + KPAIR + 8, ksl + 4096 + 512);
  gl2lds16(vstage,             vsl);
  gl2lds16(vstage + 8,         vsl + 512);
  gl2lds16(vstage + VPAIR,     vsl + 4096);
  gl2lds16(vstage + VPAIR + 8, vsl + 4096 + 512);
  kstage += KADV; vstage += VADV;

  // x2-unrolled ping-pong over buffer PAIRS (bases 0/4096 vs 8192/12288)
  int i = 0, jt = z;
  for (;;) {
    // even phase: compute pair in bufs 0,1; stage next pair into bufs 2,3
    __syncthreads();                   // drains stage issued last phase
    if (i + 1 < nst) {                 // block-uniform
      gl2lds16(kstage,             ksl + 8192);
      gl2lds16(kstage + 8,         ksl + 8192 + 512);
      gl2lds16(kstage + KPAIR,     ksl + 12288);
      gl2lds16(kstage + KPAIR + 8, ksl + 12288 + 512);
      gl2lds16(vstage,             vsl + 8192);
      gl2lds16(vstage + 8,         vsl + 8192 + 512);
      gl2lds16(vstage + VPAIR,     vsl + 12288);
      gl2lds16(vstage + VPAIR + 8, vsl + 12288 + 512);
      kstage += KADV; vstage += VADV;
    }
    subtile(jt,     ICt<0>{});         // staging latency hides under these
    subtile(jt + 2, ICt<1>{});
    ++i; jt += 4;
    if (i >= nst) break;

    // odd phase: compute pair in bufs 2,3; stage next pair into bufs 0,1
    __syncthreads();
    if (i + 1 < nst) {
      gl2lds16(kstage,             ksl);
      gl2lds16(kstage + 8,         ksl + 512);
      gl2lds16(kstage + KPAIR,     ksl + 4096);
      gl2lds16(kstage + KPAIR + 8, ksl + 4096 + 512);
      gl2lds16(vstage,             vsl);
      gl2lds16(vstage + 8,         vsl + 512);
      gl2lds16(vstage + VPAIR,     vsl + 4096);
      gl2lds16(vstage + VPAIR + 8, vsl + 4096 + 512);
      kstage += KADV; vstage += VADV;
    }
    subtile(jt,     ICt<2>{});
    subtile(jt + 2, ICt<3>{});
    ++i; jt += 4;
    if (i >= nst) break;
  }

  // ---- epilogue: plain coalesced bf16 partial stores (NO atomics)
  short* pO = z ? pO1 : pO0;
#pragma unroll
  for (int s = 0; s < 4; ++s)
#pragma unroll
    for (int nt = 0; nt < 4; ++nt)
#pragma unroll
      for (int r = 0; r < 4; ++r)
        pO[(size_t)(qw + s * 16 + quad * 4 + r) * DIM + h * HD + nt * 16 + l15] =
            f2bf(oacc[s][nt][r]);
  if (l15 == 0) {
#pragma unroll
    for (int s = 0; s < 4; ++s)
#pragma unroll
      for (int r = 0; r < 4; ++r)
        lp[(size_t)z * SEQ * NHEAD + (size_t)(qw + s * 16 + quad * 4 + r) * NHEAD + h] =
            lacc[s][r];
  }
}

// Z[q][d] = (pO0 + pO1) / (l0 + l1), bf16 out. Both splits fully written
// for every q (zero where no live subtiles). 8 elems/thread.
__global__ void combine_kernel(const short* __restrict__ pO0,
                               const short* __restrict__ pO1,
                               const float* __restrict__ lp,
                               short* __restrict__ Z) {
  size_t e = ((size_t)blockIdx.x * 256 + threadIdx.x) * 8;
  int q  = (int)(e >> 10);
  int hh = (int)((e & 1023) >> 6);
  const size_t LS = (size_t)SEQ * NHEAD;
  size_t li = (size_t)q * NHEAD + hh;
  float l = lp[li] + lp[LS + li];
  uint4v a = *(const uint4v*)(pO0 + e);
  uint4v b = *(const uint4v*)(pO1 + e);
  float s[8];
#pragma unroll
  for (int i = 0; i < 4; ++i) {
    s[2 * i]     = bflo(a[i]) + bflo(b[i]);
    s[2 * i + 1] = bfhi(a[i]) + bfhi(b[i]);
  }
  float rinv = 1.0f / l;
  uint4v o;
#pragma unroll
  for (int i = 0; i < 4; ++i) {
    unsigned p0 = (unsigned)(unsigned short)f2bf(s[2 * i] * rinv);
    unsigned p1 = (unsigned)(unsigned short)f2bf(s[2 * i + 1] * rinv);
    o[i] = p0 | (p1 << 16);
  }
  *(uint4v*)(Z + e) = o;
}

// Final O-projection: out[4096,1024] = Z[4096,1024]·Wo[1024,1024]^T, fp32 out.
// (round-6 version: DMA A-staging. The fused-combine variants of rounds
// 8-9 regressed +8..15us: reg-staged A always exposes latency because
// __syncthreads drains vmcnt. CONDEMNED -- keep the separate combine.)
// 64x128 tiles -> 512 blocks = 2 blocks/CU resident. 12 KB LDS.
__global__ __launch_bounds__(256, 2) void gemm_out(const short* __restrict__ A,
                                                   const short* __restrict__ B,
                                                   float* __restrict__ C) {
  __shared__ short As[64 * 32];   // 4 KB
  __shared__ short Bs[128 * 32];  // 8 KB
  const int tid  = threadIdx.x;
  const int wave = tid >> 6;
  const int lane = tid & 63;
  const int quad = lane >> 4;
  const int l15  = lane & 15;
  const int bm = (int)(blockIdx.x >> 3) * 64;
  const int bn = (int)(blockIdx.x & 7) * 128;
  const int wn = wave * 32;
  const int sw = (quad ^ ((l15 >> 1) & 3)) * 8;

  f32x4 acc[4][2];
#pragma unroll
  for (int i = 0; i < 4; ++i)
#pragma unroll
    for (int j = 0; j < 2; ++j) acc[i][j] = (f32x4){0.f, 0.f, 0.f, 0.f};

  for (int k0 = 0; k0 < 1024; k0 += 32) {
    {  // A: 64x32 = 256 slots, one per thread
      int c = tid;
      int row = c >> 2;
      int ce = ((c & 3) ^ ((c >> 3) & 3)) * 8;
      gl2lds16(A + (size_t)(bm + row) * 1024 + k0 + ce,
               As + (size_t)(wave * 64) * 8);
    }
#pragma unroll
    for (int it = 0; it < 2; ++it) {  // B: 128x32 = 512 slots
      int c = it * 256 + tid;
      int row = c >> 2;
      int ce = ((c & 3) ^ ((c >> 3) & 3)) * 8;
      gl2lds16(B + (size_t)(bn + row) * 1024 + k0 + ce,
               Bs + (size_t)(it * 256 + wave * 64) * 8);
    }
    __syncthreads();

    bf16x8 af[4], bfr[2];
#pragma unroll
    for (int mt = 0; mt < 4; ++mt)
      af[mt] = *(const bf16x8*)&As[(mt * 16 + l15) * 32 + sw];
#pragma unroll
    for (int nt = 0; nt < 2; ++nt)
      bfr[nt] = *(const bf16x8*)&Bs[(wn + nt * 16 + l15) * 32 + sw];
#pragma unroll
    for (int mt = 0; mt < 4; ++mt)
#pragma unroll
      for (int nt = 0; nt < 2; ++nt)
        acc[mt][nt] = __builtin_amdgcn_mfma_f32_16x16x32_bf16(
            af[mt], bfr[nt], acc[mt][nt], 0, 0, 0);
    __syncthreads();
  }

#pragma unroll
  for (int mt = 0; mt < 4; ++mt)
#pragma unroll
    for (int nt = 0; nt < 2; ++nt)
#pragma unroll
      for (int r = 0; r < 4; ++r)
        C[(size_t)(bm + mt * 16 + quad * 4 + r) * 1024 + bn + wn + nt * 16 + l15] =
            acc[mt][nt][r];
}

extern "C" void kernel_launch(void* const* d_in, const int* in_sizes, int n_in,
                              void* d_out, int out_size, void* d_ws, size_t ws_size,
                              hipStream_t stream) {
  const float* x  = (const float*)d_in[0];
  const float* Wq = (const float*)d_in[1];
  const float* Wk = (const float*)d_in[2];
  const float* Wv = (const float*)d_in[3];
  const float* Wo = (const float*)d_in[4];
  float* out = (float*)d_out;

  // Workspace layout (48 MB), regions overlaid by lifetime:
  //  [0,8)   xb (cast->proj)            ; pO0 bf16 (flash->combine)
  //  [8,12)  wq,wk (cast->proj)         ; lp fp32 [2][SEQ][NHEAD] (flash->combine)
  //  [12,14) wv (cast->proj)
  //  [14,16) wo (cast->gemm_out, live to end)
  //  [16,32) QKb bf16 (proj->flash)     ; Zb bf16 [16,24) (combine->gemm_out)
  //  [32,40) Vtb F16 (proj->flash)
  //  [40,48) pO1 bf16 (flash->combine)
  char* ws   = (char*)d_ws;
  short* xb  = (short*)(ws);
  short* wqb = (short*)(ws + (size_t)8 * 1024 * 1024);
  short* wvb = wqb + 2 * 1024 * 1024;
  short* wob = wqb + 3 * 1024 * 1024;
  short* QKb = (short*)(ws + (size_t)16 * 1024 * 1024);
  short* Vtb = (short*)(ws + (size_t)32 * 1024 * 1024);
  float* lpb = (float*)(ws + (size_t)8 * 1024 * 1024);
  short* pO0 = (short*)(ws);
  short* pO1 = (short*)(ws + (size_t)40 * 1024 * 1024);
  short* Zb  = QKb;  // over dead Q half of QKb after flash

  cast_kernel<<<dim3(8192), dim3(256), 0, stream>>>(x, Wq, Wk, Wv, Wo, xb, wqb);

  // fused Q+K projection (blocks 0..511) + V^T projection in f16 (512..767)
  proj_kernel<<<dim3(768), dim3(256), 0, stream>>>(xb, wqb, wvb, QKb, Vtb);

  flash_attn<<<dim3(512), dim3(256), 0, stream>>>(QKb, Vtb, pO0, pO1, lpb);
  combine_kernel<<<dim3(2048), dim3(256), 0, stream>>>(pO0, pO1, lpb, Zb);

  gemm_out<<<dim3(512), dim3(256), 0, stream>>>(Zb, wob, out);
}

// Round 11
// 182.934 us; speedup vs baseline: 1.1067x; 1.1011x over previous
//
#include <hip/hip_runtime.h>
#include <hip/hip_bf16.h>

#define DIM   1024
#define NHEAD 16
#define HD    64
#define SEQ   4096

typedef __attribute__((ext_vector_type(4))) float  f32x4;
typedef __attribute__((ext_vector_type(8))) __bf16 bf16x8;
typedef __attribute__((ext_vector_type(8))) _Float16 f16x8;
typedef __attribute__((ext_vector_type(4))) short  short4v;
typedef __attribute__((ext_vector_type(4))) unsigned uint4v;

template <int B> struct ICt { static constexpr int v = B; };

// fp32 -> bf16 RNE
static __device__ __forceinline__ short f2bf(float f) {
  unsigned u = __builtin_bit_cast(unsigned, f);
  u += 0x7fffu + ((u >> 16) & 1u);
  return (short)(u >> 16);
}
static __device__ __forceinline__ float bflo(unsigned u) {
  return __builtin_bit_cast(float, u << 16);
}
static __device__ __forceinline__ float bfhi(unsigned u) {
  return __builtin_bit_cast(float, u & 0xFFFF0000u);
}

// pack two fp32 -> packed f16 pair (v_cvt_pkrtz_f16_f32), as raw u32
static __device__ __forceinline__ unsigned pkf16(float a, float b) {
  return __builtin_bit_cast(unsigned, __builtin_amdgcn_cvt_pkrtz(a, b));
}

// async global->LDS, 16B per lane: per-lane GLOBAL gather, LDS dest =
// wave-uniform base + lane*16.
static __device__ __forceinline__ void gl2lds16(const void* g, void* l) {
  __builtin_amdgcn_global_load_lds(
      (__attribute__((address_space(1))) void*)g,
      (__attribute__((address_space(3))) void*)l, 16, 0, 0);
}

// Cast x + 4 weights to bf16.
__global__ void cast_kernel(const float* __restrict__ x,
                            const float* __restrict__ Wq,
                            const float* __restrict__ Wk,
                            const float* __restrict__ Wv,
                            const float* __restrict__ Wo,
                            short* __restrict__ xb,
                            short* __restrict__ wb) {
  int b = blockIdx.x;
  const float* src;
  short* dst;
  if (b < 4096) {
    src = x + (size_t)b * 1024;
    dst = xb + (size_t)b * 1024;
  } else {
    int t = b - 4096;
    int w = t >> 10;
    size_t off = (size_t)(t & 1023) * 1024;
    src = (w == 0 ? Wq : w == 1 ? Wk : w == 2 ? Wv : Wo) + off;
    dst = wb + (size_t)w * 1048576 + off;
  }
  int i = threadIdx.x;
  float4 v = ((const float4*)src)[i];
  short4v o;
  o.x = f2bf(v.x); o.y = f2bf(v.y); o.z = f2bf(v.z); o.w = f2bf(v.w);
  ((short4v*)dst)[i] = o;
}

// 128x128 NT GEMM tile body: C[M,N] = A[M,K]*B[N,K]^T, bf16 K-major inputs.
// OUT: 0 = bf16 store, 2 = f16 store.
// LDS XOR swizzle (keep): un-swizzled frag reads were 8-way bank conflicts
// (1.05M SQ_LDS_BANK_CONFLICT measured round 11).
template <int OUT>
static __device__ __forceinline__ void gemm_tile(const short* __restrict__ A,
                                                 const short* __restrict__ B,
                                                 void* __restrict__ Cv,
                                                 int N, int K, int bm, int bn,
                                                 short* As, short* Bs) {
  const int tid  = threadIdx.x;
  const int wave = tid >> 6;
  const int lane = tid & 63;
  const int quad = lane >> 4;
  const int l15  = lane & 15;
  const int wm = (wave >> 1) * 64;
  const int wn = (wave & 1) * 64;
  const int sw = (quad ^ ((l15 >> 1) & 3)) * 8;   // read-side swizzle

  f32x4 acc[4][4];
#pragma unroll
  for (int i = 0; i < 4; ++i)
#pragma unroll
    for (int j = 0; j < 4; ++j) acc[i][j] = (f32x4){0.f, 0.f, 0.f, 0.f};

  for (int k0 = 0; k0 < K; k0 += 32) {
#pragma unroll
    for (int it = 0; it < 2; ++it) {
      int c   = it * 256 + wave * 64 + lane;       // 16B slot id, 512 total
      int row = c >> 2;
      int ce  = ((c & 3) ^ ((c >> 3) & 3)) * 8;    // swizzled global col-block
      gl2lds16(A + (size_t)(bm + row) * K + k0 + ce,
               As + (size_t)(it * 256 + wave * 64) * 8);
      gl2lds16(B + (size_t)(bn + row) * K + k0 + ce,
               Bs + (size_t)(it * 256 + wave * 64) * 8);
    }
    __syncthreads();

    bf16x8 af[4], bfr[4];
#pragma unroll
    for (int mt = 0; mt < 4; ++mt)
      af[mt] = *(const bf16x8*)&As[(wm + mt * 16 + l15) * 32 + sw];
#pragma unroll
    for (int nt = 0; nt < 4; ++nt)
      bfr[nt] = *(const bf16x8*)&Bs[(wn + nt * 16 + l15) * 32 + sw];
#pragma unroll
    for (int mt = 0; mt < 4; ++mt)
#pragma unroll
      for (int nt = 0; nt < 4; ++nt)
        acc[mt][nt] = __builtin_amdgcn_mfma_f32_16x16x32_bf16(
            af[mt], bfr[nt], acc[mt][nt], 0, 0, 0);
    __syncthreads();
  }

  short* C = (short*)Cv;
#pragma unroll
  for (int mt = 0; mt < 4; ++mt)
#pragma unroll
    for (int nt = 0; nt < 4; ++nt)
#pragma unroll
      for (int r = 0; r < 4; ++r) {
        size_t idx = (size_t)(bm + wm + mt * 16 + quad * 4 + r) * N +
                     bn + wn + nt * 16 + l15;
        if (OUT == 0)
          C[idx] = f2bf(acc[mt][nt][r]);
        else
          C[idx] = (short)(pkf16(acc[mt][nt][r], 0.f) & 0xFFFFu);
      }
}

// Fused projection launch: blocks 0..511 compute QK = x·[Wq;Wk]^T (bf16,
// [4096][2048]); blocks 512..767 compute Vt = Wv·x^T (F16, [1024][4096]).
// ROUND-26 CHANGE: __launch_bounds__(256, 3) -> VGPR cap 170, 3 blocks/CU
// resident -> ALL 768 blocks in ONE generation (was 2/CU: 512-block gen
// then a 256-block gen with half the machine idle at 1 block/CU = the
// latency-exposed 2-waves/SIMD regime round-10's flash just demonstrated).
// Also +1 wave/SIMD of latency hiding throughout. Spill signature to
// watch: proj regression + WRITE balloon (then revert to (256,2)).
__global__ __launch_bounds__(256, 3) void proj_kernel(const short* __restrict__ xb,
                                                      const short* __restrict__ wqk,
                                                      const short* __restrict__ wv,
                                                      short* __restrict__ QKb,
                                                      short* __restrict__ Vtb) {
  __shared__ short As[128 * 32];
  __shared__ short Bs[128 * 32];
  int b = blockIdx.x;
  if (b < 512) {
    gemm_tile<0>(xb, wqk, QKb, 2048, 1024, (b >> 4) * 128, (b & 15) * 128, As, Bs);
  } else {
    int t = b - 512;
    gemm_tile<2>(wv, xb, Vtb, 4096, 1024, (t >> 5) * 128, (t & 31) * 128, As, Bs);
  }
}

// Flash attention, causal, key-split KS=2, NO ATOMICS. (= round-6 version,
// verified 51.7us -- the structural floor of this design. Round-7 pairing
// (55us), round-10 4x64 (91us: 2 waves/SIMD exposes dependency latency),
// rounds 8-9 fused epilogue (both regressed) are all CONDEMNED. 8 waves x
// 32 q-rows is the measured optimum of the rows/wave curve 16/32/64 ->
// 72/51/91us.)
// KS=2 with 128-key PHASES: each barrier-phase stages+computes TWO 64-key
// subtiles (4 LDS subtile buffers, 64 KB). Grid 512 = 2 blocks/CU
// all-resident. Balanced y-remap: blocks land on CUs as {c, c+256}; y =
// (t<8 ? 15-t : t-8) makes every CU's pair sum to 17 phases. 2 partial
// buffers. Single-barrier ping-pong (stage pair i+1 BEFORE compute pair i;
// one barrier per phase drains last phase's DMA), compile-time LDS bases
// via ICt, hoisted LDS base pointers, f16 PV, raw v_exp_f32, unnormalized
// partials pOz + lp[z]. launch_bounds(512,4): cap 128 VGPR (round-19's
// (512,8) spill disaster: WRITE 34->113MB must not recur).
// NEVER index a frag buffer with a runtime value (round-5 scratch spill).
__global__ __launch_bounds__(512, 4) void flash_attn(const short* __restrict__ QK,
                                                     const short* __restrict__ Vt,
                                                     short* __restrict__ pO0,
                                                     short* __restrict__ pO1,
                                                     float* __restrict__ lp) {
  const int bb  = blockIdx.x;
  const int z   = bb & 1;              // key split: 64-key tile jt ≡ z (mod 2)
  const int h   = (bb >> 1) & 15;
  const int t   = bb >> 5;             // 0..15
  const int y   = (t < 8) ? (15 - t) : (t - 8);  // balanced pairs sum 17
  // jtB = 4y+3 >= 3 > z always: every split live, nst = y+1 pair-phases.

  __shared__ short Ks[4 * 4096];       // 32 KB: 4 x 64-key K subtiles
  __shared__ short Vs[4 * 4096];       // 32 KB (f16 payload)

  const int wave = threadIdx.x >> 6;   // 0..7
  const int lane = threadIdx.x & 63;
  const int quad = lane >> 4;
  const int l15  = lane & 15;
  const int qw   = y * 256 + wave * 32;  // this wave's 32 q rows (2 strips)
  const int jtd  = 4 * y + (wave >> 1);  // diag 64-key tile for this wave

  const short* Qp = QK + h * HD;
  const short* Kp = QK + 1024 + h * HD;
  const short* Vp = Vt + (size_t)(h * HD) * SEQ;

  // Q frags (loaded once): strips A (rows qw+0..15) and B (rows qw+16..31)
  bf16x8 qf0[2], qf1[2];
#pragma unroll
  for (int kk = 0; kk < 2; ++kk) {
    qf0[kk] = *(const bf16x8*)&Qp[(size_t)(qw + l15) * 2048 + kk * 32 + quad * 8];
    qf1[kk] = *(const bf16x8*)&Qp[(size_t)(qw + 16 + l15) * 2048 + kk * 32 + quad * 8];
  }

  f32x4 oaccA[4], oaccB[4];
  f32x4 laccA = (f32x4){0.f, 0.f, 0.f, 0.f};
  f32x4 laccB = (f32x4){0.f, 0.f, 0.f, 0.f};
#pragma unroll
  for (int nt = 0; nt < 4; ++nt) {
    oaccA[nt] = (f32x4){0.f, 0.f, 0.f, 0.f};
    oaccB[nt] = (f32x4){0.f, 0.f, 0.f, 0.f};
  }

  const float SC = 0.125f * 1.44269504088896340736f;  // /sqrt(64) * log2(e)

  f16x8 ones16;
  { uint4v o1 = {0x3C003C00u, 0x3C003C00u, 0x3C003C00u, 0x3C003C00u};
    ones16 = __builtin_bit_cast(f16x8, o1); }

  // hoisted LDS read base pointers (per-subtile reads fold to
  // [invariant reg + literal offset])
  const short* kq = Ks + quad * 512 + l15 * 8;
  const short* vq = Vs + quad * 512 + l15 * 8;

  // staging: wave nw does chunk pair (nw&3, nw>>2) of each subtile:
  // 2 K + 2 V gl2lds per wave per pair-phase.
  const int ow = wave & 3;
  const int hf = wave >> 2;
  const int g = ((lane >> 5) & 1) * 32 + ((lane >> 4) & 1) * 4 +
                ((lane >> 2) & 3) * 8 + (lane & 3);
  const short* kstage = Kp + (size_t)(z * 64 + g) * 2048 + ow * 16 + hf * 8;
  const short* vstage = Vp + (size_t)lane * SEQ + z * 64 + ow * 16 + hf * 8;
  short* ksl = Ks + ow * 1024 + hf * 512;
  short* vsl = Vs + ow * 1024 + hf * 512;
  const size_t KPAIR = (size_t)2 * 64 * 2048;  // 2nd subtile of pair (jt+2)
  const size_t KADV  = (size_t)4 * 64 * 2048;  // phase stride (jt+=4)
  const int    VPAIR = 2 * 64;
  const int    VADV  = 4 * 64;

  const int qv0 = qw + l15;
  const int qv1 = qw + 16 + l15;

  // one 64-key subtile for both strips; LDS base is COMPILE-TIME
  auto subtile = [&](int jtc, auto bc) {
    constexpr int base = decltype(bc)::v * 4096;
    if (jtc > jtd) return;             // fully-masked future tile: contributes 0

    f32x4 s0[4], s1[4];
#pragma unroll
    for (int mt = 0; mt < 4; ++mt) {
      bf16x8 k0 = *(const bf16x8*)(kq + base + mt * 128);
      bf16x8 k1 = *(const bf16x8*)(kq + base + 2048 + mt * 128);
      s0[mt] = (f32x4){0.f, 0.f, 0.f, 0.f};
      s0[mt] = __builtin_amdgcn_mfma_f32_16x16x32_bf16(k0, qf0[0], s0[mt], 0, 0, 0);
      s0[mt] = __builtin_amdgcn_mfma_f32_16x16x32_bf16(k1, qf0[1], s0[mt], 0, 0, 0);
      s1[mt] = (f32x4){0.f, 0.f, 0.f, 0.f};
      s1[mt] = __builtin_amdgcn_mfma_f32_16x16x32_bf16(k0, qf1[0], s1[mt], 0, 0, 0);
      s1[mt] = __builtin_amdgcn_mfma_f32_16x16x32_bf16(k1, qf1[1], s1[mt], 0, 0, 0);
    }

    unsigned pk0[4][2], pk1[4][2];
    const bool domask = (jtc == jtd);  // wave-uniform
#pragma unroll
    for (int mt = 0; mt < 4; ++mt) {
      float pr[4], qr[4];
#pragma unroll
      for (int r = 0; r < 4; ++r) {
        pr[r] = fmaf(s0[mt][r], SC, -12.0f);
        qr[r] = fmaf(s1[mt][r], SC, -12.0f);
      }
      if (domask) {
        int kb0 = jtc * 64 + (mt >> 1) * 32 + quad * 8 + (mt & 1) * 4;
#pragma unroll
        for (int r = 0; r < 4; ++r) {
          if (kb0 + r > qv0) pr[r] = -1e30f;
          if (kb0 + r > qv1) qr[r] = -1e30f;
        }
      }
#pragma unroll
      for (int r = 0; r < 4; ++r) {
        pr[r] = __builtin_amdgcn_exp2f(pr[r]);
        qr[r] = __builtin_amdgcn_exp2f(qr[r]);
      }
      pk0[mt][0] = pkf16(pr[0], pr[1]);
      pk0[mt][1] = pkf16(pr[2], pr[3]);
      pk1[mt][0] = pkf16(qr[0], qr[1]);
      pk1[mt][1] = pkf16(qr[2], qr[3]);
    }

#pragma unroll
    for (int kk = 0; kk < 2; ++kk) {
      f16x8 vb[4];
#pragma unroll
      for (int nt = 0; nt < 4; ++nt)
        vb[nt] = *(const f16x8*)(vq + base + kk * 2048 + nt * 128);
      f16x8 pa0, pa1;
      { uint4v t2 = {pk0[2 * kk][0], pk0[2 * kk][1],
                     pk0[2 * kk + 1][0], pk0[2 * kk + 1][1]};
        pa0 = __builtin_bit_cast(f16x8, t2); }
      { uint4v t2 = {pk1[2 * kk][0], pk1[2 * kk][1],
                     pk1[2 * kk + 1][0], pk1[2 * kk + 1][1]};
        pa1 = __builtin_bit_cast(f16x8, t2); }
      laccA = __builtin_amdgcn_mfma_f32_16x16x32_f16(pa0, ones16, laccA, 0, 0, 0);
      laccB = __builtin_amdgcn_mfma_f32_16x16x32_f16(pa1, ones16, laccB, 0, 0, 0);
#pragma unroll
      for (int nt = 0; nt < 4; ++nt) {
        oaccA[nt] = __builtin_amdgcn_mfma_f32_16x16x32_f16(pa0, vb[nt], oaccA[nt], 0, 0, 0);
        oaccB[nt] = __builtin_amdgcn_mfma_f32_16x16x32_f16(pa1, vb[nt], oaccB[nt], 0, 0, 0);
      }
    }
  };

  const int nst = y + 1;               // pair-phases (uniform in z)

  // prologue: stage pair 0 (subtiles jt=z, z+2) into buffers 0,1
  gl2lds16(kstage,         ksl);
  gl2lds16(kstage + KPAIR, ksl + 4096);
  gl2lds16(vstage,         vsl);
  gl2lds16(vstage + VPAIR, vsl + 4096);
  kstage += KADV; vstage += VADV;

  // x2-unrolled ping-pong over buffer PAIRS (bases 0/4096 vs 8192/12288)
  int i = 0, jt = z;
  for (;;) {
    // even phase: compute pair in bufs 0,1; stage next pair into bufs 2,3
    __syncthreads();                   // drains stage issued last phase
    if (i + 1 < nst) {                 // block-uniform
      gl2lds16(kstage,         ksl + 8192);
      gl2lds16(kstage + KPAIR, ksl + 12288);
      gl2lds16(vstage,         vsl + 8192);
      gl2lds16(vstage + VPAIR, vsl + 12288);
      kstage += KADV; vstage += VADV;
    }
    subtile(jt,     ICt<0>{});         // staging latency hides under these
    subtile(jt + 2, ICt<1>{});
    ++i; jt += 4;
    if (i >= nst) break;

    // odd phase: compute pair in bufs 2,3; stage next pair into bufs 0,1
    __syncthreads();
    if (i + 1 < nst) {
      gl2lds16(kstage,         ksl);
      gl2lds16(kstage + KPAIR, ksl + 4096);
      gl2lds16(vstage,         vsl);
      gl2lds16(vstage + VPAIR, vsl + 4096);
      kstage += KADV; vstage += VADV;
    }
    subtile(jt,     ICt<2>{});
    subtile(jt + 2, ICt<3>{});
    ++i; jt += 4;
    if (i >= nst) break;
  }

  // ---- epilogue: plain coalesced bf16 partial stores (NO atomics)
  short* pO = z ? pO1 : pO0;
#pragma unroll
  for (int nt = 0; nt < 4; ++nt)
#pragma unroll
    for (int r = 0; r < 4; ++r) {
      pO[(size_t)(qw + quad * 4 + r) * DIM + h * HD + nt * 16 + l15] =
          f2bf(oaccA[nt][r]);
      pO[(size_t)(qw + 16 + quad * 4 + r) * DIM + h * HD + nt * 16 + l15] =
          f2bf(oaccB[nt][r]);
    }
  if (l15 == 0) {
#pragma unroll
    for (int r = 0; r < 4; ++r) {
      lp[(size_t)z * SEQ * NHEAD + (size_t)(qw + quad * 4 + r) * NHEAD + h] =
          laccA[r];
      lp[(size_t)z * SEQ * NHEAD + (size_t)(qw + 16 + quad * 4 + r) * NHEAD + h] =
          laccB[r];
    }
  }
}

// Z[q][d] = (pO0 + pO1) / (l0 + l1), bf16 out. Both splits fully written
// for every q (zero where no live subtiles). 8 elems/thread.
__global__ void combine_kernel(const short* __restrict__ pO0,
                               const short* __restrict__ pO1,
                               const float* __restrict__ lp,
                               short* __restrict__ Z) {
  size_t e = ((size_t)blockIdx.x * 256 + threadIdx.x) * 8;
  int q  = (int)(e >> 10);
  int hh = (int)((e & 1023) >> 6);
  const size_t LS = (size_t)SEQ * NHEAD;
  size_t li = (size_t)q * NHEAD + hh;
  float l = lp[li] + lp[LS + li];
  uint4v a = *(const uint4v*)(pO0 + e);
  uint4v b = *(const uint4v*)(pO1 + e);
  float s[8];
#pragma unroll
  for (int i = 0; i < 4; ++i) {
    s[2 * i]     = bflo(a[i]) + bflo(b[i]);
    s[2 * i + 1] = bfhi(a[i]) + bfhi(b[i]);
  }
  float rinv = 1.0f / l;
  uint4v o;
#pragma unroll
  for (int i = 0; i < 4; ++i) {
    unsigned p0 = (unsigned)(unsigned short)f2bf(s[2 * i] * rinv);
    unsigned p1 = (unsigned)(unsigned short)f2bf(s[2 * i + 1] * rinv);
    o[i] = p0 | (p1 << 16);
  }
  *(uint4v*)(Z + e) = o;
}

// Final O-projection: out[4096,1024] = Z[4096,1024]·Wo[1024,1024]^T, fp32 out.
// (DMA A-staging. The fused-combine variants of rounds 8-9 regressed
// +8..15us: reg-staged A always exposes latency because __syncthreads
// drains vmcnt. CONDEMNED -- keep the separate combine.)
// 64x128 tiles -> 512 blocks = 2 blocks/CU resident. 12 KB LDS.
__global__ __launch_bounds__(256, 2) void gemm_out(const short* __restrict__ A,
                                                   const short* __restrict__ B,
                                                   float* __restrict__ C) {
  __shared__ short As[64 * 32];   // 4 KB
  __shared__ short Bs[128 * 32];  // 8 KB
  const int tid  = threadIdx.x;
  const int wave = tid >> 6;
  const int lane = tid & 63;
  const int quad = lane >> 4;
  const int l15  = lane & 15;
  const int bm = (int)(blockIdx.x >> 3) * 64;
  const int bn = (int)(blockIdx.x & 7) * 128;
  const int wn = wave * 32;
  const int sw = (quad ^ ((l15 >> 1) & 3)) * 8;

  f32x4 acc[4][2];
#pragma unroll
  for (int i = 0; i < 4; ++i)
#pragma unroll
    for (int j = 0; j < 2; ++j) acc[i][j] = (f32x4){0.f, 0.f, 0.f, 0.f};

  for (int k0 = 0; k0 < 1024; k0 += 32) {
    {  // A: 64x32 = 256 slots, one per thread
      int c = tid;
      int row = c >> 2;
      int ce = ((c & 3) ^ ((c >> 3) & 3)) * 8;
      gl2lds16(A + (size_t)(bm + row) * 1024 + k0 + ce,
               As + (size_t)(wave * 64) * 8);
    }
#pragma unroll
    for (int it = 0; it < 2; ++it) {  // B: 128x32 = 512 slots
      int c = it * 256 + tid;
      int row = c >> 2;
      int ce = ((c & 3) ^ ((c >> 3) & 3)) * 8;
      gl2lds16(B + (size_t)(bn + row) * 1024 + k0 + ce,
               Bs + (size_t)(it * 256 + wave * 64) * 8);
    }
    __syncthreads();

    bf16x8 af[4], bfr[2];
#pragma unroll
    for (int mt = 0; mt < 4; ++mt)
      af[mt] = *(const bf16x8*)&As[(mt * 16 + l15) * 32 + sw];
#pragma unroll
    for (int nt = 0; nt < 2; ++nt)
      bfr[nt] = *(const bf16x8*)&Bs[(wn + nt * 16 + l15) * 32 + sw];
#pragma unroll
    for (int mt = 0; mt < 4; ++mt)
#pragma unroll
      for (int nt = 0; nt < 2; ++nt)
        acc[mt][nt] = __builtin_amdgcn_mfma_f32_16x16x32_bf16(
            af[mt], bfr[nt], acc[mt][nt], 0, 0, 0);
    __syncthreads();
  }

#pragma unroll
  for (int mt = 0; mt < 4; ++mt)
#pragma unroll
    for (int nt = 0; nt < 2; ++nt)
#pragma unroll
      for (int r = 0; r < 4; ++r)
        C[(size_t)(bm + mt * 16 + quad * 4 + r) * 1024 + bn + wn + nt * 16 + l15] =
            acc[mt][nt][r];
}

extern "C" void kernel_launch(void* const* d_in, const int* in_sizes, int n_in,
                              void* d_out, int out_size, void* d_ws, size_t ws_size,
                              hipStream_t stream) {
  const float* x  = (const float*)d_in[0];
  const float* Wq = (const float*)d_in[1];
  const float* Wk = (const float*)d_in[2];
  const float* Wv = (const float*)d_in[3];
  const float* Wo = (const float*)d_in[4];
  float* out = (float*)d_out;

  // Workspace layout (48 MB), regions overlaid by lifetime:
  //  [0,8)   xb (cast->proj)            ; pO0 bf16 (flash->combine)
  //  [8,12)  wq,wk (cast->proj)         ; lp fp32 [2][SEQ][NHEAD] (flash->combine)
  //  [12,14) wv (cast->proj)
  //  [14,16) wo (cast->gemm_out, live to end)
  //  [16,32) QKb bf16 (proj->flash)     ; Zb bf16 [16,24) (combine->gemm_out)
  //  [32,40) Vtb F16 (proj->flash)
  //  [40,48) pO1 bf16 (flash->combine)
  char* ws   = (char*)d_ws;
  short* xb  = (short*)(ws);
  short* wqb = (short*)(ws + (size_t)8 * 1024 * 1024);
  short* wvb = wqb + 2 * 1024 * 1024;
  short* wob = wqb + 3 * 1024 * 1024;
  short* QKb = (short*)(ws + (size_t)16 * 1024 * 1024);
  short* Vtb = (short*)(ws + (size_t)32 * 1024 * 1024);
  float* lpb = (float*)(ws + (size_t)8 * 1024 * 1024);
  short* pO0 = (short*)(ws);
  short* pO1 = (short*)(ws + (size_t)40 * 1024 * 1024);
  short* Zb  = QKb;  // over dead Q half of QKb after flash

  cast_kernel<<<dim3(8192), dim3(256), 0, stream>>>(x, Wq, Wk, Wv, Wo, xb, wqb);

  // fused Q+K projection (blocks 0..511) + V^T projection in f16 (512..767)
  proj_kernel<<<dim3(768), dim3(256), 0, stream>>>(xb, wqb, wvb, QKb, Vtb);

  flash_attn<<<dim3(512), dim3(512), 0, stream>>>(QKb, Vtb, pO0, pO1, lpb);
  combine_kernel<<<dim3(2048), dim3(256), 0, stream>>>(pO0, pO1, lpb, Zb);

  gemm_out<<<dim3(512), dim3(256), 0, stream>>>(Zb, wob, out);
}

// Round 14
// 179.545 us; speedup vs baseline: 1.1276x; 1.0189x over previous
//
#include <hip/hip_runtime.h>
#include <hip/hip_bf16.h>

#define DIM   1024
#define NHEAD 16
#define HD    64
#define SEQ   4096

typedef __attribute__((ext_vector_type(4))) float  f32x4;
typedef __attribute__((ext_vector_type(8))) __bf16 bf16x8;
typedef __attribute__((ext_vector_type(8))) _Float16 f16x8;
typedef __attribute__((ext_vector_type(4))) short  short4v;
typedef __attribute__((ext_vector_type(4))) unsigned uint4v;

template <int B> struct ICt { static constexpr int v = B; };

// fp32 -> bf16 RNE
static __device__ __forceinline__ short f2bf(float f) {
  unsigned u = __builtin_bit_cast(unsigned, f);
  u += 0x7fffu + ((u >> 16) & 1u);
  return (short)(u >> 16);
}
static __device__ __forceinline__ float bflo(unsigned u) {
  return __builtin_bit_cast(float, u << 16);
}
static __device__ __forceinline__ float bfhi(unsigned u) {
  return __builtin_bit_cast(float, u & 0xFFFF0000u);
}

// pack two fp32 -> packed f16 pair (v_cvt_pkrtz_f16_f32), as raw u32
static __device__ __forceinline__ unsigned pkf16(float a, float b) {
  return __builtin_bit_cast(unsigned, __builtin_amdgcn_cvt_pkrtz(a, b));
}

// async global->LDS, 16B per lane: per-lane GLOBAL gather, LDS dest =
// wave-uniform base + lane*16.
static __device__ __forceinline__ void gl2lds16(const void* g, void* l) {
  __builtin_amdgcn_global_load_lds(
      (__attribute__((address_space(1))) void*)g,
      (__attribute__((address_space(3))) void*)l, 16, 0, 0);
}

// Cast x + 4 weights to bf16.
__global__ void cast_kernel(const float* __restrict__ x,
                            const float* __restrict__ Wq,
                            const float* __restrict__ Wk,
                            const float* __restrict__ Wv,
                            const float* __restrict__ Wo,
                            short* __restrict__ xb,
                            short* __restrict__ wb) {
  int b = blockIdx.x;
  const float* src;
  short* dst;
  if (b < 4096) {
    src = x + (size_t)b * 1024;
    dst = xb + (size_t)b * 1024;
  } else {
    int t = b - 4096;
    int w = t >> 10;
    size_t off = (size_t)(t & 1023) * 1024;
    src = (w == 0 ? Wq : w == 1 ? Wk : w == 2 ? Wv : Wo) + off;
    dst = wb + (size_t)w * 1048576 + off;
  }
  int i = threadIdx.x;
  float4 v = ((const float4*)src)[i];
  short4v o;
  o.x = f2bf(v.x); o.y = f2bf(v.y); o.z = f2bf(v.z); o.w = f2bf(v.w);
  ((short4v*)dst)[i] = o;
}

// 128x128 NT GEMM tile body: C[M,N] = A[M,K]*B[N,K]^T, bf16 K-major inputs.
// OUT: 0 = bf16 store, 2 = f16 store.
// ROUND-27 CHANGE (resubmitted rounds 28-29 after broker timeouts -- never
// ran): BK=64 (was 32). Each k-step's two __syncthreads carry a full
// vmcnt(0) drain (~600-800 cyc, the m97-structure stall); 32 steps x 2
// barriers was pure overhead scaling with K-steps, not FLOPs. BK=64 halves
// it: 16 steps, 32 barriers. LDS 16->32 KB (3 blocks/CU = 96 KB ok); per-K
// staging volume unchanged (8 gl2lds/thread/step). Swizzle re-derived for
// 8-slot (128 B) rows: WRITE pre-swizzles the GLOBAL column (LDS stays
// linear -- gl2lds requires it): ce = ((c&7)^((c>>3)&7))*8, key=row&7.
// READ: slot = (kk*4+quad)^(l15&7) -> lanes 0-7 hit 8 distinct bank-quads,
// lanes 8-15 alias 2-way (free, m136). kk ascending preserves accumulation
// order -> bit-identical results.
template <int OUT>
static __device__ __forceinline__ void gemm_tile(const short* __restrict__ A,
                                                 const short* __restrict__ B,
                                                 void* __restrict__ Cv,
                                                 int N, int K, int bm, int bn,
                                                 short* As, short* Bs) {
  const int tid  = threadIdx.x;
  const int wave = tid >> 6;
  const int lane = tid & 63;
  const int quad = lane >> 4;
  const int l15  = lane & 15;
  const int wm = (wave >> 1) * 64;
  const int wn = (wave & 1) * 64;

  f32x4 acc[4][4];
#pragma unroll
  for (int i = 0; i < 4; ++i)
#pragma unroll
    for (int j = 0; j < 4; ++j) acc[i][j] = (f32x4){0.f, 0.f, 0.f, 0.f};

  for (int k0 = 0; k0 < K; k0 += 64) {
#pragma unroll
    for (int it = 0; it < 4; ++it) {
      int c   = it * 256 + wave * 64 + lane;       // 16B slot id, 1024 total
      int row = c >> 3;
      int ce  = ((c & 7) ^ ((c >> 3) & 7)) * 8;    // swizzled global col-block
      gl2lds16(A + (size_t)(bm + row) * K + k0 + ce,
               As + (size_t)(it * 256 + wave * 64) * 8);
      gl2lds16(B + (size_t)(bn + row) * K + k0 + ce,
               Bs + (size_t)(it * 256 + wave * 64) * 8);
    }
    __syncthreads();

#pragma unroll
    for (int kk = 0; kk < 2; ++kk) {
      const int sw2 = (((kk << 2) + quad) ^ (l15 & 7)) * 8;  // read-side swizzle
      bf16x8 af[4], bfr[4];
#pragma unroll
      for (int mt = 0; mt < 4; ++mt)
        af[mt] = *(const bf16x8*)&As[(wm + mt * 16 + l15) * 64 + sw2];
#pragma unroll
      for (int nt = 0; nt < 4; ++nt)
        bfr[nt] = *(const bf16x8*)&Bs[(wn + nt * 16 + l15) * 64 + sw2];
#pragma unroll
      for (int mt = 0; mt < 4; ++mt)
#pragma unroll
        for (int nt = 0; nt < 4; ++nt)
          acc[mt][nt] = __builtin_amdgcn_mfma_f32_16x16x32_bf16(
              af[mt], bfr[nt], acc[mt][nt], 0, 0, 0);
    }
    __syncthreads();
  }

  short* C = (short*)Cv;
#pragma unroll
  for (int mt = 0; mt < 4; ++mt)
#pragma unroll
    for (int nt = 0; nt < 4; ++nt)
#pragma unroll
      for (int r = 0; r < 4; ++r) {
        size_t idx = (size_t)(bm + wm + mt * 16 + quad * 4 + r) * N +
                     bn + wn + nt * 16 + l15;
        if (OUT == 0)
          C[idx] = f2bf(acc[mt][nt][r]);
        else
          C[idx] = (short)(pkf16(acc[mt][nt][r], 0.f) & 0xFFFFu);
      }
}

// Fused projection launch: blocks 0..511 compute QK = x·[Wq;Wk]^T (bf16,
// [4096][2048]); blocks 512..767 compute Vt = Wv·x^T (F16, [1024][4096]).
// launch_bounds(256,3): VGPR cap 170, 3 blocks/CU -> all 768 blocks in ONE
// generation (round-26 win). LDS now 32 KB/block -> 96 KB/CU, still fits.
__global__ __launch_bounds__(256, 3) void proj_kernel(const short* __restrict__ xb,
                                                      const short* __restrict__ wqk,
                                                      const short* __restrict__ wv,
                                                      short* __restrict__ QKb,
                                                      short* __restrict__ Vtb) {
  __shared__ short As[128 * 64];
  __shared__ short Bs[128 * 64];
  int b = blockIdx.x;
  if (b < 512) {
    gemm_tile<0>(xb, wqk, QKb, 2048, 1024, (b >> 4) * 128, (b & 15) * 128, As, Bs);
  } else {
    int t = b - 512;
    gemm_tile<2>(wv, xb, Vtb, 4096, 1024, (t >> 5) * 128, (t & 31) * 128, As, Bs);
  }
}

// Flash attention, causal, key-split KS=2, NO ATOMICS. (= round-6 version,
// verified 51.7us -- the structural floor of this design. Round-7 pairing
// (55us), round-10 4x64 (91us: 2 waves/SIMD exposes dependency latency),
// rounds 8-9 fused epilogue (both regressed) are all CONDEMNED. 8 waves x
// 32 q-rows is the measured optimum of the rows/wave curve 16/32/64 ->
// 72/51/91us. NOTE: this kernel's dur wobbles 51-59us across sessions with
// identical code -- environment/clock noise band, don't chase.)
// KS=2 with 128-key PHASES: each barrier-phase stages+computes TWO 64-key
// subtiles (4 LDS subtile buffers, 64 KB). Grid 512 = 2 blocks/CU
// all-resident. Balanced y-remap: blocks land on CUs as {c, c+256}; y =
// (t<8 ? 15-t : t-8) makes every CU's pair sum to 17 phases. 2 partial
// buffers. Single-barrier ping-pong (stage pair i+1 BEFORE compute pair i;
// one barrier per phase drains last phase's DMA), compile-time LDS bases
// via ICt, hoisted LDS base pointers, f16 PV, raw v_exp_f32, unnormalized
// partials pOz + lp[z]. launch_bounds(512,4): cap 128 VGPR (round-19's
// (512,8) spill disaster: WRITE 34->113MB must not recur).
// NEVER index a frag buffer with a runtime value (round-5 scratch spill).
__global__ __launch_bounds__(512, 4) void flash_attn(const short* __restrict__ QK,
                                                     const short* __restrict__ Vt,
                                                     short* __restrict__ pO0,
                                                     short* __restrict__ pO1,
                                                     float* __restrict__ lp) {
  const int bb  = blockIdx.x;
  const int z   = bb & 1;              // key split: 64-key tile jt ≡ z (mod 2)
  const int h   = (bb >> 1) & 15;
  const int t   = bb >> 5;             // 0..15
  const int y   = (t < 8) ? (15 - t) : (t - 8);  // balanced pairs sum 17
  // jtB = 4y+3 >= 3 > z always: every split live, nst = y+1 pair-phases.

  __shared__ short Ks[4 * 4096];       // 32 KB: 4 x 64-key K subtiles
  __shared__ short Vs[4 * 4096];       // 32 KB (f16 payload)

  const int wave = threadIdx.x >> 6;   // 0..7
  const int lane = threadIdx.x & 63;
  const int quad = lane >> 4;
  const int l15  = lane & 15;
  const int qw   = y * 256 + wave * 32;  // this wave's 32 q rows (2 strips)
  const int jtd  = 4 * y + (wave >> 1);  // diag 64-key tile for this wave

  const short* Qp = QK + h * HD;
  const short* Kp = QK + 1024 + h * HD;
  const short* Vp = Vt + (size_t)(h * HD) * SEQ;

  // Q frags (loaded once): strips A (rows qw+0..15) and B (rows qw+16..31)
  bf16x8 qf0[2], qf1[2];
#pragma unroll
  for (int kk = 0; kk < 2; ++kk) {
    qf0[kk] = *(const bf16x8*)&Qp[(size_t)(qw + l15) * 2048 + kk * 32 + quad * 8];
    qf1[kk] = *(const bf16x8*)&Qp[(size_t)(qw + 16 + l15) * 2048 + kk * 32 + quad * 8];
  }

  f32x4 oaccA[4], oaccB[4];
  f32x4 laccA = (f32x4){0.f, 0.f, 0.f, 0.f};
  f32x4 laccB = (f32x4){0.f, 0.f, 0.f, 0.f};
#pragma unroll
  for (int nt = 0; nt < 4; ++nt) {
    oaccA[nt] = (f32x4){0.f, 0.f, 0.f, 0.f};
    oaccB[nt] = (f32x4){0.f, 0.f, 0.f, 0.f};
  }

  const float SC = 0.125f * 1.44269504088896340736f;  // /sqrt(64) * log2(e)

  f16x8 ones16;
  { uint4v o1 = {0x3C003C00u, 0x3C003C00u, 0x3C003C00u, 0x3C003C00u};
    ones16 = __builtin_bit_cast(f16x8, o1); }

  // hoisted LDS read base pointers (per-subtile reads fold to
  // [invariant reg + literal offset])
  const short* kq = Ks + quad * 512 + l15 * 8;
  const short* vq = Vs + quad * 512 + l15 * 8;

  // staging: wave nw does chunk pair (nw&3, nw>>2) of each subtile:
  // 2 K + 2 V gl2lds per wave per pair-phase.
  const int ow = wave & 3;
  const int hf = wave >> 2;
  const int g = ((lane >> 5) & 1) * 32 + ((lane >> 4) & 1) * 4 +
                ((lane >> 2) & 3) * 8 + (lane & 3);
  const short* kstage = Kp + (size_t)(z * 64 + g) * 2048 + ow * 16 + hf * 8;
  const short* vstage = Vp + (size_t)lane * SEQ + z * 64 + ow * 16 + hf * 8;
  short* ksl = Ks + ow * 1024 + hf * 512;
  short* vsl = Vs + ow * 1024 + hf * 512;
  const size_t KPAIR = (size_t)2 * 64 * 2048;  // 2nd subtile of pair (jt+2)
  const size_t KADV  = (size_t)4 * 64 * 2048;  // phase stride (jt+=4)
  const int    VPAIR = 2 * 64;
  const int    VADV  = 4 * 64;

  const int qv0 = qw + l15;
  const int qv1 = qw + 16 + l15;

  // one 64-key subtile for both strips; LDS base is COMPILE-TIME
  auto subtile = [&](int jtc, auto bc) {
    constexpr int base = decltype(bc)::v * 4096;
    if (jtc > jtd) return;             // fully-masked future tile: contributes 0

    f32x4 s0[4], s1[4];
#pragma unroll
    for (int mt = 0; mt < 4; ++mt) {
      bf16x8 k0 = *(const bf16x8*)(kq + base + mt * 128);
      bf16x8 k1 = *(const bf16x8*)(kq + base + 2048 + mt * 128);
      s0[mt] = (f32x4){0.f, 0.f, 0.f, 0.f};
      s0[mt] = __builtin_amdgcn_mfma_f32_16x16x32_bf16(k0, qf0[0], s0[mt], 0, 0, 0);
      s0[mt] = __builtin_amdgcn_mfma_f32_16x16x32_bf16(k1, qf0[1], s0[mt], 0, 0, 0);
      s1[mt] = (f32x4){0.f, 0.f, 0.f, 0.f};
      s1[mt] = __builtin_amdgcn_mfma_f32_16x16x32_bf16(k0, qf1[0], s1[mt], 0, 0, 0);
      s1[mt] = __builtin_amdgcn_mfma_f32_16x16x32_bf16(k1, qf1[1], s1[mt], 0, 0, 0);
    }

    unsigned pk0[4][2], pk1[4][2];
    const bool domask = (jtc == jtd);  // wave-uniform
#pragma unroll
    for (int mt = 0; mt < 4; ++mt) {
      float pr[4], qr[4];
#pragma unroll
      for (int r = 0; r < 4; ++r) {
        pr[r] = fmaf(s0[mt][r], SC, -12.0f);
        qr[r] = fmaf(s1[mt][r], SC, -12.0f);
      }
      if (domask) {
        int kb0 = jtc * 64 + (mt >> 1) * 32 + quad * 8 + (mt & 1) * 4;
#pragma unroll
        for (int r = 0; r < 4; ++r) {
          if (kb0 + r > qv0) pr[r] = -1e30f;
          if (kb0 + r > qv1) qr[r] = -1e30f;
        }
      }
#pragma unroll
      for (int r = 0; r < 4; ++r) {
        pr[r] = __builtin_amdgcn_exp2f(pr[r]);
        qr[r] = __builtin_amdgcn_exp2f(qr[r]);
      }
      pk0[mt][0] = pkf16(pr[0], pr[1]);
      pk0[mt][1] = pkf16(pr[2], pr[3]);
      pk1[mt][0] = pkf16(qr[0], qr[1]);
      pk1[mt][1] = pkf16(qr[2], qr[3]);
    }

#pragma unroll
    for (int kk = 0; kk < 2; ++kk) {
      f16x8 vb[4];
#pragma unroll
      for (int nt = 0; nt < 4; ++nt)
        vb[nt] = *(const f16x8*)(vq + base + kk * 2048 + nt * 128);
      f16x8 pa0, pa1;
      { uint4v t2 = {pk0[2 * kk][0], pk0[2 * kk][1],
                     pk0[2 * kk + 1][0], pk0[2 * kk + 1][1]};
        pa0 = __builtin_bit_cast(f16x8, t2); }
      { uint4v t2 = {pk1[2 * kk][0], pk1[2 * kk][1],
                     pk1[2 * kk + 1][0], pk1[2 * kk + 1][1]};
        pa1 = __builtin_bit_cast(f16x8, t2); }
      laccA = __builtin_amdgcn_mfma_f32_16x16x32_f16(pa0, ones16, laccA, 0, 0, 0);
      laccB = __builtin_amdgcn_mfma_f32_16x16x32_f16(pa1, ones16, laccB, 0, 0, 0);
#pragma unroll
      for (int nt = 0; nt < 4; ++nt) {
        oaccA[nt] = __builtin_amdgcn_mfma_f32_16x16x32_f16(pa0, vb[nt], oaccA[nt], 0, 0, 0);
        oaccB[nt] = __builtin_amdgcn_mfma_f32_16x16x32_f16(pa1, vb[nt], oaccB[nt], 0, 0, 0);
      }
    }
  };

  const int nst = y + 1;               // pair-phases (uniform in z)

  // prologue: stage pair 0 (subtiles jt=z, z+2) into buffers 0,1
  gl2lds16(kstage,         ksl);
  gl2lds16(kstage + KPAIR, ksl + 4096);
  gl2lds16(vstage,         vsl);
  gl2lds16(vstage + VPAIR, vsl + 4096);
  kstage += KADV; vstage += VADV;

  // x2-unrolled ping-pong over buffer PAIRS (bases 0/4096 vs 8192/12288)
  int i = 0, jt = z;
  for (;;) {
    // even phase: compute pair in bufs 0,1; stage next pair into bufs 2,3
    __syncthreads();                   // drains stage issued last phase
    if (i + 1 < nst) {                 // block-uniform
      gl2lds16(kstage,         ksl + 8192);
      gl2lds16(kstage + KPAIR, ksl + 12288);
      gl2lds16(vstage,         vsl + 8192);
      gl2lds16(vstage + VPAIR, vsl + 12288);
      kstage += KADV; vstage += VADV;
    }
    subtile(jt,     ICt<0>{});         // staging latency hides under these
    subtile(jt + 2, ICt<1>{});
    ++i; jt += 4;
    if (i >= nst) break;

    // odd phase: compute pair in bufs 2,3; stage next pair into bufs 0,1
    __syncthreads();
    if (i + 1 < nst) {
      gl2lds16(kstage,         ksl);
      gl2lds16(kstage + KPAIR, ksl + 4096);
      gl2lds16(vstage,         vsl);
      gl2lds16(vstage + VPAIR, vsl + 4096);
      kstage += KADV; vstage += VADV;
    }
    subtile(jt,     ICt<2>{});
    subtile(jt + 2, ICt<3>{});
    ++i; jt += 4;
    if (i >= nst) break;
  }

  // ---- epilogue: plain coalesced bf16 partial stores (NO atomics)
  short* pO = z ? pO1 : pO0;
#pragma unroll
  for (int nt = 0; nt < 4; ++nt)
#pragma unroll
    for (int r = 0; r < 4; ++r) {
      pO[(size_t)(qw + quad * 4 + r) * DIM + h * HD + nt * 16 + l15] =
          f2bf(oaccA[nt][r]);
      pO[(size_t)(qw + 16 + quad * 4 + r) * DIM + h * HD + nt * 16 + l15] =
          f2bf(oaccB[nt][r]);
    }
  if (l15 == 0) {
#pragma unroll
    for (int r = 0; r < 4; ++r) {
      lp[(size_t)z * SEQ * NHEAD + (size_t)(qw + quad * 4 + r) * NHEAD + h] =
          laccA[r];
      lp[(size_t)z * SEQ * NHEAD + (size_t)(qw + 16 + quad * 4 + r) * NHEAD + h] =
          laccB[r];
    }
  }
}

// Z[q][d] = (pO0 + pO1) / (l0 + l1), bf16 out. Both splits fully written
// for every q (zero where no live subtiles). 8 elems/thread.
__global__ void combine_kernel(const short* __restrict__ pO0,
                               const short* __restrict__ pO1,
                               const float* __restrict__ lp,
                               short* __restrict__ Z) {
  size_t e = ((size_t)blockIdx.x * 256 + threadIdx.x) * 8;
  int q  = (int)(e >> 10);
  int hh = (int)((e & 1023) >> 6);
  const size_t LS = (size_t)SEQ * NHEAD;
  size_t li = (size_t)q * NHEAD + hh;
  float l = lp[li] + lp[LS + li];
  uint4v a = *(const uint4v*)(pO0 + e);
  uint4v b = *(const uint4v*)(pO1 + e);
  float s[8];
#pragma unroll
  for (int i = 0; i < 4; ++i) {
    s[2 * i]     = bflo(a[i]) + bflo(b[i]);
    s[2 * i + 1] = bfhi(a[i]) + bfhi(b[i]);
  }
  float rinv = 1.0f / l;
  uint4v o;
#pragma unroll
  for (int i = 0; i < 4; ++i) {
    unsigned p0 = (unsigned)(unsigned short)f2bf(s[2 * i] * rinv);
    unsigned p1 = (unsigned)(unsigned short)f2bf(s[2 * i + 1] * rinv);
    o[i] = p0 | (p1 << 16);
  }
  *(uint4v*)(Z + e) = o;
}

// Final O-projection: out[4096,1024] = Z[4096,1024]·Wo[1024,1024]^T, fp32 out.
// (DMA A-staging. The fused-combine variants of rounds 8-9 regressed
// +8..15us: reg-staged A always exposes latency because __syncthreads
// drains vmcnt. CONDEMNED -- keep the separate combine.)
// 64x128 tiles -> 512 blocks = 2 blocks/CU resident. 12 KB LDS.
__global__ __launch_bounds__(256, 2) void gemm_out(const short* __restrict__ A,
                                                   const short* __restrict__ B,
                                                   float* __restrict__ C) {
  __shared__ short As[64 * 32];   // 4 KB
  __shared__ short Bs[128 * 32];  // 8 KB
  const int tid  = threadIdx.x;
  const int wave = tid >> 6;
  const int lane = tid & 63;
  const int quad = lane >> 4;
  const int l15  = lane & 15;
  const int bm = (int)(blockIdx.x >> 3) * 64;
  const int bn = (int)(blockIdx.x & 7) * 128;
  const int wn = wave * 32;
  const int sw = (quad ^ ((l15 >> 1) & 3)) * 8;

  f32x4 acc[4][2];
#pragma unroll
  for (int i = 0; i < 4; ++i)
#pragma unroll
    for (int j = 0; j < 2; ++j) acc[i][j] = (f32x4){0.f, 0.f, 0.f, 0.f};

  for (int k0 = 0; k0 < 1024; k0 += 32) {
    {  // A: 64x32 = 256 slots, one per thread
      int c = tid;
      int row = c >> 2;
      int ce = ((c & 3) ^ ((c >> 3) & 3)) * 8;
      gl2lds16(A + (size_t)(bm + row) * 1024 + k0 + ce,
               As + (size_t)(wave * 64) * 8);
    }
#pragma unroll
    for (int it = 0; it < 2; ++it) {  // B: 128x32 = 512 slots
      int c = it * 256 + tid;
      int row = c >> 2;
      int ce = ((c & 3) ^ ((c >> 3) & 3)) * 8;
      gl2lds16(B + (size_t)(bn + row) * 1024 + k0 + ce,
               Bs + (size_t)(it * 256 + wave * 64) * 8);
    }
    __syncthreads();

    bf16x8 af[4], bfr[2];
#pragma unroll
    for (int mt = 0; mt < 4; ++mt)
      af[mt] = *(const bf16x8*)&As[(mt * 16 + l15) * 32 + sw];
#pragma unroll
    for (int nt = 0; nt < 2; ++nt)
      bfr[nt] = *(const bf16x8*)&Bs[(wn + nt * 16 + l15) * 32 + sw];
#pragma unroll
    for (int mt = 0; mt < 4; ++mt)
#pragma unroll
      for (int nt = 0; nt < 2; ++nt)
        acc[mt][nt] = __builtin_amdgcn_mfma_f32_16x16x32_bf16(
            af[mt], bfr[nt], acc[mt][nt], 0, 0, 0);
    __syncthreads();
  }

#pragma unroll
  for (int mt = 0; mt < 4; ++mt)
#pragma unroll
    for (int nt = 0; nt < 2; ++nt)
#pragma unroll
      for (int r = 0; r < 4; ++r)
        C[(size_t)(bm + mt * 16 + quad * 4 + r) * 1024 + bn + wn + nt * 16 + l15] =
            acc[mt][nt][r];
}

extern "C" void kernel_launch(void* const* d_in, const int* in_sizes, int n_in,
                              void* d_out, int out_size, void* d_ws, size_t ws_size,
                              hipStream_t stream) {
  const float* x  = (const float*)d_in[0];
  const float* Wq = (const float*)d_in[1];
  const float* Wk = (const float*)d_in[2];
  const float* Wv = (const float*)d_in[3];
  const float* Wo = (const float*)d_in[4];
  float* out = (float*)d_out;

  // Workspace layout (48 MB), regions overlaid by lifetime:
  //  [0,8)   xb (cast->proj)            ; pO0 bf16 (flash->combine)
  //  [8,12)  wq,wk (cast->proj)         ; lp fp32 [2][SEQ][NHEAD] (flash->combine)
  //  [12,14) wv (cast->proj)
  //  [14,16) wo (cast->gemm_out, live to end)
  //  [16,32) QKb bf16 (proj->flash)     ; Zb bf16 [16,24) (combine->gemm_out)
  //  [32,40) Vtb F16 (proj->flash)
  //  [40,48) pO1 bf16 (flash->combine)
  char* ws   = (char*)d_ws;
  short* xb  = (short*)(ws);
  short* wqb = (short*)(ws + (size_t)8 * 1024 * 1024);
  short* wvb = wqb + 2 * 1024 * 1024;
  short* wob = wqb + 3 * 1024 * 1024;
  short* QKb = (short*)(ws + (size_t)16 * 1024 * 1024);
  short* Vtb = (short*)(ws + (size_t)32 * 1024 * 1024);
  float* lpb = (float*)(ws + (size_t)8 * 1024 * 1024);
  short* pO0 = (short*)(ws);
  short* pO1 = (short*)(ws + (size_t)40 * 1024 * 1024);
  short* Zb  = QKb;  // over dead Q half of QKb after flash

  cast_kernel<<<dim3(8192), dim3(256), 0, stream>>>(x, Wq, Wk, Wv, Wo, xb, wqb);

  // fused Q+K projection (blocks 0..511) + V^T projection in f16 (512..767)
  proj_kernel<<<dim3(768), dim3(256), 0, stream>>>(xb, wqb, wvb, QKb, Vtb);

  flash_attn<<<dim3(512), dim3(512), 0, stream>>>(QKb, Vtb, pO0, pO1, lpb);
  combine_kernel<<<dim3(2048), dim3(256), 0, stream>>>(pO0, pO1, lpb, Zb);

  gemm_out<<<dim3(512), dim3(256), 0, stream>>>(Zb, wob, out);
}